// Round 1
// baseline (1880.584 us; speedup 1.0000x reference)
//
#include <hip/hip_runtime.h>
#include <hip/hip_bf16.h>
#include <stdint.h>

#define B_ 32
#define S_ 64
#define E_ 512
#define H_ 1024
#define V_ 32000
#define H3_ 3072

typedef __bf16 bf16x8 __attribute__((ext_vector_type(8)));
typedef float f32x4 __attribute__((ext_vector_type(4)));
using bf16 = __hip_bfloat16;

__device__ __forceinline__ unsigned short f2bf(float f) {
  __hip_bfloat16 h = __float2bfloat16(f);
  return __builtin_bit_cast(unsigned short, h);
}

__device__ __forceinline__ void async16(void* lds, const void* g) {
  __builtin_amdgcn_global_load_lds(
      (const __attribute__((address_space(1))) unsigned int*)g,
      (__attribute__((address_space(3))) unsigned int*)lds, 16, 0, 0);
}

// ---------------- precompute kernels ----------------

// out_W fp32 -> bf16, vectorized
__global__ void cvt_wb(const float* __restrict__ W, ushort* __restrict__ Wb, long n4) {
  long stride = (long)gridDim.x * blockDim.x;
  for (long i = (long)blockIdx.x * blockDim.x + threadIdx.x; i < n4; i += stride) {
    f32x4 v = *(const f32x4*)(W + i * 4);
    ushort4 o;
    o.x = f2bf(v[0]); o.y = f2bf(v[1]); o.z = f2bf(v[2]); o.w = f2bf(v[3]);
    ((ushort4*)Wb)[i] = o;
  }
}

// gather tok_embed rows per (t,b), convert to bf16.  Row m = t*32 + b.
__global__ void gather_tok(const int* __restrict__ toks, const float* __restrict__ emb,
                           bf16* __restrict__ Abf) {
  int m = blockIdx.x;
  int b = m & 31, t = m >> 5;
  int token = toks[b * S_ + t];
  const float* src = emb + (size_t)token * E_;
  bf16* dst = Abf + (size_t)m * E_;
  int k = threadIdx.x * 4;
  f32x4 v = *(const f32x4*)(src + k);
  dst[k + 0] = __float2bfloat16(v[0]);
  dst[k + 1] = __float2bfloat16(v[1]);
  dst[k + 2] = __float2bfloat16(v[2]);
  dst[k + 3] = __float2bfloat16(v[3]);
}

// W_ih[:, 0:512] slice -> bf16 [3072][512]
__global__ void cvt_wihx(const float* __restrict__ Wih, bf16* __restrict__ Wx) {
  int j = blockIdx.x;
  int k = threadIdx.x * 4;
  f32x4 v = *(const f32x4*)(Wih + (size_t)j * 1024 + k);
  bf16* d = Wx + (size_t)j * 512 + k;
  d[0] = __float2bfloat16(v[0]);
  d[1] = __float2bfloat16(v[1]);
  d[2] = __float2bfloat16(v[2]);
  d[3] = __float2bfloat16(v[3]);
}

// h0 = tanh(image @ init_h_W.T + b)  -> hT layout [H][B]
__global__ void h0_kernel(const float* __restrict__ img, const float* __restrict__ W,
                          const float* __restrict__ bias, float* __restrict__ hT) {
  __shared__ float sim[B_][E_ + 1];
  int tid = threadIdx.x;
  for (int i = tid; i < B_ * E_ / 4; i += 256) {
    f32x4 v = ((const f32x4*)img)[i];
    int r = (i * 4) / E_, c = (i * 4) % E_;
    sim[r][c + 0] = v[0]; sim[r][c + 1] = v[1]; sim[r][c + 2] = v[2]; sim[r][c + 3] = v[3];
  }
  __syncthreads();
  int b = tid & 31, il = tid >> 5;
  int i = blockIdx.x * 8 + il;
  const float* wr = W + (size_t)i * E_;
  float acc = 0.f;
  for (int k = 0; k < E_; k += 4) {
    f32x4 w4 = *(const f32x4*)(wr + k);
    acc += w4[0] * sim[b][k] + w4[1] * sim[b][k + 1] + w4[2] * sim[b][k + 2] + w4[3] * sim[b][k + 3];
  }
  hT[i * B_ + b] = tanhf(acc + bias[i]);
}

// u = image @ W_ih[:,512:].T, v = retr @ W_ih[:,512:].T   -> [B][3H]
__global__ void uv_kernel(const float* __restrict__ img, const float* __restrict__ retr,
                          const float* __restrict__ Wih, float* __restrict__ u,
                          float* __restrict__ v) {
  int blk = blockIdx.x;
  bool isU = blk < 384;
  const float* src = isU ? img : retr;
  float* dst = isU ? u : v;
  int j0 = (isU ? blk : blk - 384) * 8;
  __shared__ float sim[B_][E_ + 1];
  int tid = threadIdx.x;
  for (int i = tid; i < B_ * E_ / 4; i += 256) {
    f32x4 vv = ((const f32x4*)src)[i];
    int r = (i * 4) / E_, c = (i * 4) % E_;
    sim[r][c + 0] = vv[0]; sim[r][c + 1] = vv[1]; sim[r][c + 2] = vv[2]; sim[r][c + 3] = vv[3];
  }
  __syncthreads();
  int b = tid & 31;
  int j = j0 + (tid >> 5);
  const float* wr = Wih + (size_t)j * 1024 + 512;
  float acc = 0.f;
  for (int k = 0; k < E_; k += 4) {
    f32x4 w4 = *(const f32x4*)(wr + k);
    acc += w4[0] * sim[b][k] + w4[1] * sim[b][k + 1] + w4[2] * sim[b][k + 2] + w4[3] * sim[b][k + 3];
  }
  dst[b * H3_ + j] = acc;
}

// c_gate[b] = image_b . gW[1024:1536] + retr_b . gW[1536:2048] + gate_b
__global__ void cgate_kernel(const float* __restrict__ img, const float* __restrict__ retr,
                             const float* __restrict__ gW, const float* __restrict__ gb,
                             float* __restrict__ cg) {
  int b = blockIdx.x, tid = threadIdx.x;
  float acc = 0.f;
  for (int k = tid; k < E_; k += 256)
    acc += img[b * E_ + k] * gW[1024 + k] + retr[b * E_ + k] * gW[1536 + k];
  __shared__ float red[256];
  red[tid] = acc;
  __syncthreads();
  for (int s = 128; s > 0; s >>= 1) {
    if (tid < s) red[tid] += red[tid + s];
    __syncthreads();
  }
  if (tid == 0) cg[b] = red[0] + gb[0];
}

// ---------------- sequential GRU step ----------------
// grid 256 blocks x 256 threads; block covers i in [blk*4, blk*4+4), all 32 b.
__global__ __launch_bounds__(256) void step_kernel(
    const float* __restrict__ hOld, float* __restrict__ hNew,
    const float* __restrict__ gixAll, const float* __restrict__ u,
    const float* __restrict__ v, const float* __restrict__ cg,
    const float* __restrict__ gW, const float* __restrict__ Whh,
    const float* __restrict__ bih, const float* __restrict__ bhh,
    bf16* __restrict__ Hb, int t) {
  __shared__ float als[8][33];
  __shared__ float alpha_sh[32];
  __shared__ float comb[3][128];
  int tid = threadIdx.x;
  int b = tid & 31;

  // alpha = sigmoid(h . gW[0:1024] + c_gate[b])  (redundant per block, cheap)
  {
    int kc = tid >> 5;
    float p = 0.f;
    int k0 = kc * 128;
    for (int k = k0; k < k0 + 128; ++k) p += hOld[k * B_ + b] * gW[k];
    als[kc][b] = p;
  }
  __syncthreads();
  if (tid < 32) {
    float s = 0.f;
    for (int kc = 0; kc < 8; ++kc) s += als[kc][tid];
    alpha_sh[tid] = 1.f / (1.f + expf(-(s + cg[tid])));
  }
  __syncthreads();

  int il = (tid >> 5) & 3;
  int kh = tid >> 7;  // K-half
  int i = blockIdx.x * 4 + il;
  const float* wr = Whh + (size_t)i * H_;
  const float* wz = Whh + (size_t)(H_ + i) * H_;
  const float* wn = Whh + (size_t)(2 * H_ + i) * H_;
  float ar = 0.f, az = 0.f, an = 0.f;
  int k0 = kh * 512;
  for (int k = k0; k < k0 + 512; k += 4) {
    float h0v = hOld[(k + 0) * B_ + b];
    float h1v = hOld[(k + 1) * B_ + b];
    float h2v = hOld[(k + 2) * B_ + b];
    float h3v = hOld[(k + 3) * B_ + b];
    f32x4 r4 = *(const f32x4*)(wr + k);
    f32x4 z4 = *(const f32x4*)(wz + k);
    f32x4 n4 = *(const f32x4*)(wn + k);
    ar += r4[0] * h0v + r4[1] * h1v + r4[2] * h2v + r4[3] * h3v;
    az += z4[0] * h0v + z4[1] * h1v + z4[2] * h2v + z4[3] * h3v;
    an += n4[0] * h0v + n4[1] * h1v + n4[2] * h2v + n4[3] * h3v;
  }
  int x = il * 32 + b;
  if (kh == 1) {
    comb[0][x] = ar; comb[1][x] = az; comb[2][x] = an;
  }
  __syncthreads();
  if (kh == 0) {
    ar += comb[0][x]; az += comb[1][x]; an += comb[2][x];
    const float* gix = gixAll + ((size_t)t * B_ + b) * H3_;
    float a = alpha_sh[b];
    float ur = u[b * H3_ + i],        vr = v[b * H3_ + i];
    float uz = u[b * H3_ + H_ + i],   vz = v[b * H3_ + H_ + i];
    float un = u[b * H3_ + 2 * H_ + i], vn = v[b * H3_ + 2 * H_ + i];
    float ir = gix[i] + a * ur + (1.f - a) * vr + bih[i];
    float iz = gix[H_ + i] + a * uz + (1.f - a) * vz + bih[H_ + i];
    float in_ = gix[2 * H_ + i] + a * un + (1.f - a) * vn + bih[2 * H_ + i];
    float hr = ar + bhh[i];
    float hz = az + bhh[H_ + i];
    float hn = an + bhh[2 * H_ + i];
    float r = 1.f / (1.f + expf(-(ir + hr)));
    float z = 1.f / (1.f + expf(-(iz + hz)));
    float nn = tanhf(in_ + r * hn);
    float hold = hOld[i * B_ + b];
    float hv = (1.f - z) * nn + z * hold;
    hNew[i * B_ + b] = hv;
    Hb[((size_t)b * S_ + t) * H_ + i] = __float2bfloat16(hv);  // row = b*64+t
  }
}

// ---------------- bf16 MFMA GEMM:  C[M,N] = A[M,K] . Bt[N,K]^T (+bias) ----------------
// BM=BN=128, BK=32, 256 threads (4 waves, each 64x64).  M,N,K multiples of 128/128/32.
__global__ __launch_bounds__(256) void gemm_bt(const bf16* __restrict__ A,
                                               const bf16* __restrict__ Bt,
                                               const float* __restrict__ bias,
                                               float* __restrict__ C, int M, int N, int K) {
  __shared__ bf16 Ald[128 * 32];
  __shared__ bf16 Bld[128 * 32];
  int ntiles = N >> 7;
  int tm = blockIdx.x / ntiles, tn = blockIdx.x % ntiles;
  int tid = threadIdx.x;
  int l = tid & 63, w = tid >> 6;

  const bf16* ga = A + (size_t)(tm * 128 + w * 16 + (l >> 2)) * K + (l & 3) * 8;
  const bf16* gb = Bt + (size_t)(tn * 128 + w * 16 + (l >> 2)) * K + (l & 3) * 8;
  char* lA = (char*)Ald + w * 1024;
  char* lB = (char*)Bld + w * 1024;

  f32x4 acc[4][4] = {};
  int wm = (w >> 1) * 64, wn = (w & 1) * 64;
  int lr = l & 15, lk = (l >> 4) * 8;

  for (int kt = 0; kt < K; kt += 32) {
    async16(lA, ga);
    async16(lA + 4096, ga + (size_t)64 * K);
    async16(lB, gb);
    async16(lB + 4096, gb + (size_t)64 * K);
    ga += 32; gb += 32;
    __syncthreads();
    bf16x8 af[4], bfv[4];
#pragma unroll
    for (int mi = 0; mi < 4; ++mi) af[mi] = *(const bf16x8*)&Ald[(wm + mi * 16 + lr) * 32 + lk];
#pragma unroll
    for (int ni = 0; ni < 4; ++ni) bfv[ni] = *(const bf16x8*)&Bld[(wn + ni * 16 + lr) * 32 + lk];
#pragma unroll
    for (int mi = 0; mi < 4; ++mi)
#pragma unroll
      for (int ni = 0; ni < 4; ++ni)
        acc[mi][ni] = __builtin_amdgcn_mfma_f32_16x16x32_bf16(af[mi], bfv[ni], acc[mi][ni], 0, 0, 0);
    __syncthreads();
  }

  int cr = (l >> 4) * 4, cc = l & 15;
#pragma unroll
  for (int mi = 0; mi < 4; ++mi) {
#pragma unroll
    for (int ni = 0; ni < 4; ++ni) {
      int col = tn * 128 + wn + ni * 16 + cc;
      float bv = bias ? bias[col] : 0.f;
#pragma unroll
      for (int rr = 0; rr < 4; ++rr) {
        int row = tm * 128 + wm + mi * 16 + cr + rr;
        C[(size_t)row * N + col] = acc[mi][ni][rr] + bv;
      }
    }
  }
}

// ---------------- launcher ----------------
extern "C" void kernel_launch(void* const* d_in, const int* in_sizes, int n_in, void* d_out,
                              int out_size, void* d_ws, size_t ws_size, hipStream_t stream) {
  const float* img  = (const float*)d_in[0];
  const float* retr = (const float*)d_in[1];
  const int*   toks = (const int*)d_in[2];
  const float* temb = (const float*)d_in[3];
  const float* ihW  = (const float*)d_in[4];
  const float* ihb  = (const float*)d_in[5];
  const float* Wih  = (const float*)d_in[6];
  const float* Whh  = (const float*)d_in[7];
  const float* bih  = (const float*)d_in[8];
  const float* bhh  = (const float*)d_in[9];
  const float* gW   = (const float*)d_in[10];
  const float* gb   = (const float*)d_in[11];
  const float* outW = (const float*)d_in[12];
  const float* outb = (const float*)d_in[13];
  float* out = (float*)d_out;

  char* ws = (char*)d_ws;
  bf16* Wb    = (bf16*)ws;  ws += (size_t)V_ * H_ * 2;        // 65,536,000
  float* gix  = (float*)ws; ws += (size_t)S_ * B_ * H3_ * 4;  // 25,165,824
  bf16* Wihx  = (bf16*)ws;  ws += (size_t)H3_ * E_ * 2;       //  3,145,728
  bf16* Abf   = (bf16*)ws;  ws += (size_t)B_ * S_ * E_ * 2;   //  2,097,152
  bf16* Hb    = (bf16*)ws;  ws += (size_t)B_ * S_ * H_ * 2;   //  4,194,304
  float* u    = (float*)ws; ws += (size_t)B_ * H3_ * 4;
  float* v    = (float*)ws; ws += (size_t)B_ * H3_ * 4;
  float* hT0  = (float*)ws; ws += (size_t)H_ * B_ * 4;
  float* hT1  = (float*)ws; ws += (size_t)H_ * B_ * 4;
  float* cg   = (float*)ws; ws += 128;

  // precompute (parallel work)
  cvt_wb<<<2048, 256, 0, stream>>>(outW, (ushort*)Wb, (long)V_ * H_ / 4);
  gather_tok<<<B_ * S_, 128, 0, stream>>>(toks, temb, Abf);
  cvt_wihx<<<H3_, 128, 0, stream>>>(Wih, Wihx);
  gemm_bt<<<(B_ * S_ / 128) * (H3_ / 128), 256, 0, stream>>>(Abf, Wihx, nullptr, gix,
                                                             B_ * S_, H3_, E_);
  h0_kernel<<<H_ / 8, 256, 0, stream>>>(img, ihW, ihb, hT0);
  uv_kernel<<<768, 256, 0, stream>>>(img, retr, Wih, u, v);
  cgate_kernel<<<B_, 256, 0, stream>>>(img, retr, gW, gb, cg);

  // sequential recurrence
  float* hbuf[2] = {hT0, hT1};
  for (int t = 0; t < S_; ++t)
    step_kernel<<<H_ / 4, 256, 0, stream>>>(hbuf[t & 1], hbuf[(t + 1) & 1], gix, u, v, cg, gW,
                                            Whh, bih, bhh, Hb, t);

  // big output GEMM: [2048, 32000] = Hb . Wb^T + out_b
  gemm_bt<<<(B_ * S_ / 128) * (V_ / 128), 256, 0, stream>>>(Hb, Wb, outb, out,
                                                            B_ * S_, V_, H_);
}

// Round 2
// 1290.310 us; speedup vs baseline: 1.4575x; 1.4575x over previous
//
#include <hip/hip_runtime.h>
#include <hip/hip_bf16.h>
#include <stdint.h>

#define B_ 32
#define S_ 64
#define E_ 512
#define H_ 1024
#define V_ 32000
#define H3_ 3072
#define NBLK 64   // persistent kernel blocks

typedef __bf16 bf16x8 __attribute__((ext_vector_type(8)));
typedef float f32x4 __attribute__((ext_vector_type(4)));
using bf16 = __hip_bfloat16;

__device__ __forceinline__ unsigned short f2bf(float f) {
  __hip_bfloat16 h = __float2bfloat16(f);
  return __builtin_bit_cast(unsigned short, h);
}

__device__ __forceinline__ void async16(void* lds, const void* g) {
  __builtin_amdgcn_global_load_lds(
      (const __attribute__((address_space(1))) unsigned int*)g,
      (__attribute__((address_space(3))) unsigned int*)lds, 16, 0, 0);
}

// fragment-swizzled h layout: element h[b][ig] lives at this bf16 offset
__device__ __forceinline__ int hswz(int b, int ig) {
  return ((((b >> 4) * 32 + (ig >> 5)) * 64) + ((b & 15) + (((ig >> 3) & 3) << 4))) * 8 + (ig & 7);
}

// ---------------- precompute kernels ----------------

__global__ void cvt_wb(const float* __restrict__ W, ushort* __restrict__ Wb, long n4) {
  long stride = (long)gridDim.x * blockDim.x;
  for (long i = (long)blockIdx.x * blockDim.x + threadIdx.x; i < n4; i += stride) {
    f32x4 v = *(const f32x4*)(W + i * 4);
    ushort4 o;
    o.x = f2bf(v[0]); o.y = f2bf(v[1]); o.z = f2bf(v[2]); o.w = f2bf(v[3]);
    ((ushort4*)Wb)[i] = o;
  }
}

// Whh fp32 -> hi/lo bf16 split
__global__ void cvt_whh(const float* __restrict__ W, bf16* __restrict__ hi,
                        bf16* __restrict__ lo) {
  size_t idx = ((size_t)blockIdx.x * 256 + threadIdx.x) * 4;
  f32x4 v = *(const f32x4*)(W + idx);
#pragma unroll
  for (int j = 0; j < 4; ++j) {
    bf16 h = __float2bfloat16(v[j]);
    hi[idx + j] = h;
    lo[idx + j] = __float2bfloat16(v[j] - __bfloat162float(h));
  }
}

__global__ void gather_tok(const int* __restrict__ toks, const float* __restrict__ emb,
                           bf16* __restrict__ Abf) {
  int m = blockIdx.x;
  int b = m & 31, t = m >> 5;
  int token = toks[b * S_ + t];
  const float* src = emb + (size_t)token * E_;
  bf16* dst = Abf + (size_t)m * E_;
  int k = threadIdx.x * 4;
  f32x4 v = *(const f32x4*)(src + k);
  dst[k + 0] = __float2bfloat16(v[0]);
  dst[k + 1] = __float2bfloat16(v[1]);
  dst[k + 2] = __float2bfloat16(v[2]);
  dst[k + 3] = __float2bfloat16(v[3]);
}

__global__ void cvt_wihx(const float* __restrict__ Wih, bf16* __restrict__ Wx) {
  int j = blockIdx.x;
  int k = threadIdx.x * 4;
  f32x4 v = *(const f32x4*)(Wih + (size_t)j * 1024 + k);
  bf16* d = Wx + (size_t)j * 512 + k;
  d[0] = __float2bfloat16(v[0]);
  d[1] = __float2bfloat16(v[1]);
  d[2] = __float2bfloat16(v[2]);
  d[3] = __float2bfloat16(v[3]);
}

// h0 = tanh(image @ init_h_W.T + b) -> h32init [b][i], hbf buf0 (swizzled hi/lo)
__global__ void h0_kernel(const float* __restrict__ img, const float* __restrict__ W,
                          const float* __restrict__ bias, float* __restrict__ h32,
                          bf16* __restrict__ hbf0) {
  __shared__ float sim[B_][E_ + 1];
  int tid = threadIdx.x;
  for (int i = tid; i < B_ * E_ / 4; i += 256) {
    f32x4 v = ((const f32x4*)img)[i];
    int r = (i * 4) / E_, c = (i * 4) % E_;
    sim[r][c + 0] = v[0]; sim[r][c + 1] = v[1]; sim[r][c + 2] = v[2]; sim[r][c + 3] = v[3];
  }
  __syncthreads();
  int b = tid & 31, il = tid >> 5;
  int i = blockIdx.x * 8 + il;
  const float* wr = W + (size_t)i * E_;
  float acc = 0.f;
  for (int k = 0; k < E_; k += 4) {
    f32x4 w4 = *(const f32x4*)(wr + k);
    acc += w4[0] * sim[b][k] + w4[1] * sim[b][k + 1] + w4[2] * sim[b][k + 2] + w4[3] * sim[b][k + 3];
  }
  float hv = tanhf(acc + bias[i]);
  h32[b * H_ + i] = hv;
  bf16 h16 = __float2bfloat16(hv);
  int off = hswz(b, i);
  hbf0[off] = h16;
  hbf0[32768 + off] = __float2bfloat16(hv - __bfloat162float(h16));
}

__global__ void uv_kernel(const float* __restrict__ img, const float* __restrict__ retr,
                          const float* __restrict__ Wih, float* __restrict__ u,
                          float* __restrict__ v) {
  int blk = blockIdx.x;
  bool isU = blk < 384;
  const float* src = isU ? img : retr;
  float* dst = isU ? u : v;
  int j0 = (isU ? blk : blk - 384) * 8;
  __shared__ float sim[B_][E_ + 1];
  int tid = threadIdx.x;
  for (int i = tid; i < B_ * E_ / 4; i += 256) {
    f32x4 vv = ((const f32x4*)src)[i];
    int r = (i * 4) / E_, c = (i * 4) % E_;
    sim[r][c + 0] = vv[0]; sim[r][c + 1] = vv[1]; sim[r][c + 2] = vv[2]; sim[r][c + 3] = vv[3];
  }
  __syncthreads();
  int b = tid & 31;
  int j = j0 + (tid >> 5);
  const float* wr = Wih + (size_t)j * 1024 + 512;
  float acc = 0.f;
  for (int k = 0; k < E_; k += 4) {
    f32x4 w4 = *(const f32x4*)(wr + k);
    acc += w4[0] * sim[b][k] + w4[1] * sim[b][k + 1] + w4[2] * sim[b][k + 2] + w4[3] * sim[b][k + 3];
  }
  dst[b * H3_ + j] = acc;
}

__global__ void cgate_kernel(const float* __restrict__ img, const float* __restrict__ retr,
                             const float* __restrict__ gW, const float* __restrict__ gb,
                             float* __restrict__ cg) {
  int b = blockIdx.x, tid = threadIdx.x;
  float acc = 0.f;
  for (int k = tid; k < E_; k += 256)
    acc += img[b * E_ + k] * gW[1024 + k] + retr[b * E_ + k] * gW[1536 + k];
  __shared__ float red[256];
  red[tid] = acc;
  __syncthreads();
  for (int s = 128; s > 0; s >>= 1) {
    if (tid < s) red[tid] += red[tid + s];
    __syncthreads();
  }
  if (tid == 0) cg[b] = red[0] + gb[0];
}

// ---------------- grid barrier (device-scope) ----------------
__device__ __forceinline__ void grid_barrier(unsigned* cnt, unsigned* gen, unsigned nblk) {
  __syncthreads();
  if (threadIdx.x == 0) {
    __threadfence();
    unsigned g = __hip_atomic_load(gen, __ATOMIC_RELAXED, __HIP_MEMORY_SCOPE_AGENT);
    unsigned old = __hip_atomic_fetch_add(cnt, 1, __ATOMIC_ACQ_REL, __HIP_MEMORY_SCOPE_AGENT);
    if (old == nblk - 1) {
      __hip_atomic_store(cnt, 0u, __ATOMIC_RELAXED, __HIP_MEMORY_SCOPE_AGENT);
      __hip_atomic_store(gen, g + 1, __ATOMIC_RELEASE, __HIP_MEMORY_SCOPE_AGENT);
    } else {
      while (__hip_atomic_load(gen, __ATOMIC_ACQUIRE, __HIP_MEMORY_SCOPE_AGENT) == g)
        __builtin_amdgcn_s_sleep(2);
    }
    __threadfence();
  }
  __syncthreads();
}

// ---------------- persistent GRU recurrence ----------------
// 64 blocks x 256 threads. Block bi owns i-slice [bi*16, bi*16+16) of all 3 gates.
// Whh hi/lo slice lives in registers as MFMA B-fragments (wave w = K-chunk w*256).
__global__ __launch_bounds__(256, 1) void gru_persist(
    const bf16* __restrict__ WhhHi, const bf16* __restrict__ WhhLo,
    const float* __restrict__ gixAll, const float* __restrict__ u,
    const float* __restrict__ v, const float* __restrict__ cg,
    const float* __restrict__ gW, const float* __restrict__ bih,
    const float* __restrict__ bhh, const float* __restrict__ h32init,
    bf16* __restrict__ hbf, float* __restrict__ pg, unsigned* __restrict__ bar,
    bf16* __restrict__ Hb) {
  int bi = blockIdx.x;
  int tid = threadIdx.x;
  int w = tid >> 6, l = tid & 63;
  int lr = l & 15, lk8 = (l >> 4) * 8;
  int kbase = w * 256;

  __shared__ float red[4][3][2][64][4];  // 24KB: [kchunk][gate][btile][lane][reg]
  __shared__ float als[8][32];
  __shared__ float alpha_sh[32];
  __shared__ float pgt[32][8];

  // ---- preload Whh hi/lo fragments (192 VGPRs) ----
  bf16x8 whi[3][8], wlo[3][8];
#pragma unroll
  for (int g = 0; g < 3; ++g)
#pragma unroll
    for (int ks = 0; ks < 8; ++ks) {
      size_t off = (size_t)(g * H_ + bi * 16 + lr) * H_ + kbase + ks * 32 + lk8;
      whi[g][ks] = *(const bf16x8*)(WhhHi + off);
      wlo[g][ks] = *(const bf16x8*)(WhhLo + off);
    }

  // ---- per-thread step-invariant scalars (outputs o=2*tid, 2*tid+1) ----
  int bq = tid >> 3;
  int il0 = (tid & 7) * 2;
  float uq[2][3], vq[2][3], biq[2][3], bhq[2][3], gwq[2], hold[2];
#pragma unroll
  for (int q = 0; q < 2; ++q) {
    int ig = bi * 16 + il0 + q;
#pragma unroll
    for (int g = 0; g < 3; ++g) {
      uq[q][g] = u[bq * H3_ + g * H_ + ig];
      vq[q][g] = v[bq * H3_ + g * H_ + ig];
      biq[q][g] = bih[g * H_ + ig];
      bhq[q][g] = bhh[g * H_ + ig];
    }
    gwq[q] = gW[ig];
    hold[q] = h32init[bq * H_ + ig];
  }

  // ---- prologue: pg partial for step 0 ----
  {
    float p = hold[0] * gwq[0] + hold[1] * gwq[1];
    pgt[bq][tid & 7] = p;
    __syncthreads();
    if (tid < 32) {
      float s = 0.f;
#pragma unroll
      for (int j = 0; j < 8; ++j) s += pgt[tid][j];
      pg[bi * 32 + tid] = s;
    }
  }
  grid_barrier(bar, bar + 32, NBLK);

  for (int t = 0; t < S_; ++t) {
    int cur = t & 1, nxt = cur ^ 1;

    // ---- alpha from pg[cur] ----
    {
      int b = tid & 31, c = tid >> 5;
      const float* p = pg + cur * 2048 + c * 8 * 32 + b;
      float s = 0.f;
#pragma unroll
      for (int j = 0; j < 8; ++j) s += p[j * 32];
      als[c][b] = s;
    }
    __syncthreads();
    if (tid < 32) {
      float s = cg[tid];
#pragma unroll
      for (int c = 0; c < 8; ++c) s += als[c][tid];
      alpha_sh[tid] = 1.f / (1.f + expf(-s));
    }
    __syncthreads();

    // ---- MFMA: gh partials over this wave's K-chunk ----
    const bf16* hb = hbf + (size_t)cur * 65536;
    f32x4 acc[3][2] = {};
#pragma unroll
    for (int ks = 0; ks < 8; ++ks) {
#pragma unroll
      for (int bt = 0; bt < 2; ++bt) {
        size_t hoff = ((size_t)(bt * 32 + w * 8 + ks) * 64 + l) * 8;
        bf16x8 hh = *(const bf16x8*)(hb + hoff);
        bf16x8 hl = *(const bf16x8*)(hb + 32768 + hoff);
#pragma unroll
        for (int g = 0; g < 3; ++g) {
          acc[g][bt] = __builtin_amdgcn_mfma_f32_16x16x32_bf16(hh, whi[g][ks], acc[g][bt], 0, 0, 0);
          acc[g][bt] = __builtin_amdgcn_mfma_f32_16x16x32_bf16(hl, whi[g][ks], acc[g][bt], 0, 0, 0);
          acc[g][bt] = __builtin_amdgcn_mfma_f32_16x16x32_bf16(hh, wlo[g][ks], acc[g][bt], 0, 0, 0);
        }
      }
    }
#pragma unroll
    for (int g = 0; g < 3; ++g)
#pragma unroll
      for (int bt = 0; bt < 2; ++bt)
        *(f32x4*)&red[w][g][bt][l][0] = acc[g][bt];
    __syncthreads();

    // ---- update: 2 outputs per thread ----
    float a = alpha_sh[bq];
    int btq = bq >> 4, breg = bq & 3, lrow = ((bq & 15) >> 2) * 16;
    const float* gx = gixAll + ((size_t)t * B_ + bq) * H3_;
    float pgp = 0.f;
    bf16* hbn = hbf + (size_t)nxt * 65536;
#pragma unroll
    for (int q = 0; q < 2; ++q) {
      int il = il0 + q;
      int ig = bi * 16 + il;
      int lane = lrow + il;
      float sr = red[0][0][btq][lane][breg] + red[1][0][btq][lane][breg] +
                 red[2][0][btq][lane][breg] + red[3][0][btq][lane][breg];
      float sz = red[0][1][btq][lane][breg] + red[1][1][btq][lane][breg] +
                 red[2][1][btq][lane][breg] + red[3][1][btq][lane][breg];
      float sn = red[0][2][btq][lane][breg] + red[1][2][btq][lane][breg] +
                 red[2][2][btq][lane][breg] + red[3][2][btq][lane][breg];
      float ir = gx[ig] + a * uq[q][0] + (1.f - a) * vq[q][0] + biq[q][0];
      float iz = gx[H_ + ig] + a * uq[q][1] + (1.f - a) * vq[q][1] + biq[q][1];
      float in_ = gx[2 * H_ + ig] + a * uq[q][2] + (1.f - a) * vq[q][2] + biq[q][2];
      float r = 1.f / (1.f + expf(-(ir + sr + bhq[q][0])));
      float z = 1.f / (1.f + expf(-(iz + sz + bhq[q][1])));
      float nn = tanhf(in_ + r * (sn + bhq[q][2]));
      float hv = (1.f - z) * nn + z * hold[q];
      hold[q] = hv;
      bf16 h16 = __float2bfloat16(hv);
      int off = hswz(bq, ig);
      hbn[off] = h16;
      hbn[32768 + off] = __float2bfloat16(hv - __bfloat162float(h16));
      Hb[((size_t)bq * S_ + t) * H_ + ig] = h16;
      pgp += hv * gwq[q];
    }
    pgt[bq][tid & 7] = pgp;
    __syncthreads();
    if (tid < 32) {
      float s = 0.f;
#pragma unroll
      for (int j = 0; j < 8; ++j) s += pgt[tid][j];
      pg[nxt * 2048 + bi * 32 + tid] = s;
    }
    if (t < S_ - 1) grid_barrier(bar, bar + 32, NBLK);
  }
}

// ---------------- bf16 MFMA GEMM:  C[M,N] = A[M,K] . Bt[N,K]^T (+bias) ----------------
__global__ __launch_bounds__(256) void gemm_bt(const bf16* __restrict__ A,
                                               const bf16* __restrict__ Bt,
                                               const float* __restrict__ bias,
                                               float* __restrict__ C, int M, int N, int K) {
  __shared__ bf16 Ald[128 * 32];
  __shared__ bf16 Bld[128 * 32];
  int nb = gridDim.x;
  int bid = blockIdx.x;
  int swz = bid;
  if ((nb & 7) == 0) swz = (bid & 7) * (nb >> 3) + (bid >> 3);  // XCD-chunked
  int mtiles = M >> 7;
  int tm = swz % mtiles, tn = swz / mtiles;  // tm fast => B-tile reuse in L2
  int tid = threadIdx.x;
  int l = tid & 63, w = tid >> 6;

  const bf16* ga = A + (size_t)(tm * 128 + w * 16 + (l >> 2)) * K + (l & 3) * 8;
  const bf16* gb = Bt + (size_t)(tn * 128 + w * 16 + (l >> 2)) * K + (l & 3) * 8;
  char* lA = (char*)Ald + w * 1024;
  char* lB = (char*)Bld + w * 1024;

  f32x4 acc[4][4] = {};
  int wm = (w >> 1) * 64, wn = (w & 1) * 64;
  int lr = l & 15, lk = (l >> 4) * 8;

  for (int kt = 0; kt < K; kt += 32) {
    async16(lA, ga);
    async16(lA + 4096, ga + (size_t)64 * K);
    async16(lB, gb);
    async16(lB + 4096, gb + (size_t)64 * K);
    ga += 32; gb += 32;
    __syncthreads();
    bf16x8 af[4], bfv[4];
#pragma unroll
    for (int mi = 0; mi < 4; ++mi) af[mi] = *(const bf16x8*)&Ald[(wm + mi * 16 + lr) * 32 + lk];
#pragma unroll
    for (int ni = 0; ni < 4; ++ni) bfv[ni] = *(const bf16x8*)&Bld[(wn + ni * 16 + lr) * 32 + lk];
#pragma unroll
    for (int mi = 0; mi < 4; ++mi)
#pragma unroll
      for (int ni = 0; ni < 4; ++ni)
        acc[mi][ni] = __builtin_amdgcn_mfma_f32_16x16x32_bf16(af[mi], bfv[ni], acc[mi][ni], 0, 0, 0);
    __syncthreads();
  }

  int cr = (l >> 4) * 4, cc = l & 15;
#pragma unroll
  for (int mi = 0; mi < 4; ++mi) {
#pragma unroll
    for (int ni = 0; ni < 4; ++ni) {
      int col = tn * 128 + wn + ni * 16 + cc;
      float bv = bias ? bias[col] : 0.f;
#pragma unroll
      for (int rr = 0; rr < 4; ++rr) {
        int row = tm * 128 + wm + mi * 16 + cr + rr;
        C[(size_t)row * N + col] = acc[mi][ni][rr] + bv;
      }
    }
  }
}

// ---------------- launcher ----------------
extern "C" void kernel_launch(void* const* d_in, const int* in_sizes, int n_in, void* d_out,
                              int out_size, void* d_ws, size_t ws_size, hipStream_t stream) {
  const float* img  = (const float*)d_in[0];
  const float* retr = (const float*)d_in[1];
  const int*   toks = (const int*)d_in[2];
  const float* temb = (const float*)d_in[3];
  const float* ihW  = (const float*)d_in[4];
  const float* ihb  = (const float*)d_in[5];
  const float* Wih  = (const float*)d_in[6];
  const float* Whh  = (const float*)d_in[7];
  const float* bih  = (const float*)d_in[8];
  const float* bhh  = (const float*)d_in[9];
  const float* gW   = (const float*)d_in[10];
  const float* gb   = (const float*)d_in[11];
  const float* outW = (const float*)d_in[12];
  const float* outb = (const float*)d_in[13];
  float* out = (float*)d_out;

  char* ws = (char*)d_ws;
  bf16* Wb     = (bf16*)ws;  ws += (size_t)V_ * H_ * 2;
  float* gix   = (float*)ws; ws += (size_t)S_ * B_ * H3_ * 4;
  bf16* WhhHi  = (bf16*)ws;  ws += (size_t)H3_ * H_ * 2;
  bf16* WhhLo  = (bf16*)ws;  ws += (size_t)H3_ * H_ * 2;
  bf16* Wihx   = (bf16*)ws;  ws += (size_t)H3_ * E_ * 2;
  bf16* Abf    = (bf16*)ws;  ws += (size_t)B_ * S_ * E_ * 2;
  bf16* Hb     = (bf16*)ws;  ws += (size_t)B_ * S_ * H_ * 2;
  float* u     = (float*)ws; ws += (size_t)B_ * H3_ * 4;
  float* v     = (float*)ws; ws += (size_t)B_ * H3_ * 4;
  float* h32i  = (float*)ws; ws += (size_t)B_ * H_ * 4;
  bf16* hbf    = (bf16*)ws;  ws += (size_t)2 * 2 * B_ * H_ * 2;  // [buf][hi|lo] swizzled
  float* pg    = (float*)ws; ws += (size_t)2 * NBLK * B_ * 4;
  float* cg    = (float*)ws; ws += 128;
  unsigned* bar = (unsigned*)ws; ws += 256;

  // precompute
  cvt_wb<<<2048, 256, 0, stream>>>(outW, (ushort*)Wb, (long)V_ * H_ / 4);
  gather_tok<<<B_ * S_, 128, 0, stream>>>(toks, temb, Abf);
  cvt_wihx<<<H3_, 128, 0, stream>>>(Wih, Wihx);
  gemm_bt<<<(B_ * S_ / 128) * (H3_ / 128), 256, 0, stream>>>(Abf, Wihx, nullptr, gix,
                                                             B_ * S_, H3_, E_);
  cvt_whh<<<H3_ * H_ / 1024, 256, 0, stream>>>(Whh, WhhHi, WhhLo);
  h0_kernel<<<H_ / 8, 256, 0, stream>>>(img, ihW, ihb, h32i, hbf);
  uv_kernel<<<768, 256, 0, stream>>>(img, retr, Wih, u, v);
  cgate_kernel<<<B_, 256, 0, stream>>>(img, retr, gW, gb, cg);
  hipMemsetAsync(bar, 0, 256, stream);

  // persistent recurrence (all 64 steps, one launch)
  gru_persist<<<NBLK, 256, 0, stream>>>(WhhHi, WhhLo, gix, u, v, cg, gW, bih, bhh, h32i,
                                        hbf, pg, bar, Hb);

  // big output GEMM: [2048, 32000] = Hb . Wb^T + out_b
  gemm_bt<<<(B_ * S_ / 128) * (V_ / 128), 256, 0, stream>>>(Hb, Wb, outb, out,
                                                            B_ * S_, V_, H_);
}

// Round 4
// 1175.290 us; speedup vs baseline: 1.6001x; 1.0979x over previous
//
#include <hip/hip_runtime.h>
#include <hip/hip_bf16.h>
#include <stdint.h>

#define B_ 32
#define S_ 64
#define E_ 512
#define H_ 1024
#define V_ 32000
#define H3_ 3072
#define NBLK 64   // persistent kernel blocks

typedef __bf16 bf16x8 __attribute__((ext_vector_type(8)));
typedef float f32x4 __attribute__((ext_vector_type(4)));
using bf16 = __hip_bfloat16;

__device__ __forceinline__ unsigned short f2bf(float f) {
  __hip_bfloat16 h = __float2bfloat16(f);
  return __builtin_bit_cast(unsigned short, h);
}

__device__ __forceinline__ void async16(void* lds, const void* g) {
  __builtin_amdgcn_global_load_lds(
      (const __attribute__((address_space(1))) unsigned int*)g,
      (__attribute__((address_space(3))) unsigned int*)lds, 16, 0, 0);
}

// fragment-swizzled h layout: element h[b][ig] lives at this bf16 offset
__device__ __forceinline__ int hswz(int b, int ig) {
  return ((((b >> 4) * 32 + (ig >> 5)) * 64) + ((b & 15) + (((ig >> 3) & 3) << 4))) * 8 + (ig & 7);
}

// ---------------- precompute kernels ----------------

__global__ void cvt_wb(const float* __restrict__ W, ushort* __restrict__ Wb, long n4) {
  long stride = (long)gridDim.x * blockDim.x;
  for (long i = (long)blockIdx.x * blockDim.x + threadIdx.x; i < n4; i += stride) {
    f32x4 v = *(const f32x4*)(W + i * 4);
    ushort4 o;
    o.x = f2bf(v[0]); o.y = f2bf(v[1]); o.z = f2bf(v[2]); o.w = f2bf(v[3]);
    ((ushort4*)Wb)[i] = o;
  }
}

// Whh fp32 -> hi/lo bf16 split
__global__ void cvt_whh(const float* __restrict__ W, bf16* __restrict__ hi,
                        bf16* __restrict__ lo) {
  size_t idx = ((size_t)blockIdx.x * 256 + threadIdx.x) * 4;
  f32x4 v = *(const f32x4*)(W + idx);
#pragma unroll
  for (int j = 0; j < 4; ++j) {
    bf16 h = __float2bfloat16(v[j]);
    hi[idx + j] = h;
    lo[idx + j] = __float2bfloat16(v[j] - __bfloat162float(h));
  }
}

__global__ void gather_tok(const int* __restrict__ toks, const float* __restrict__ emb,
                           bf16* __restrict__ Abf) {
  int m = blockIdx.x;
  int b = m & 31, t = m >> 5;
  int token = toks[b * S_ + t];
  const float* src = emb + (size_t)token * E_;
  bf16* dst = Abf + (size_t)m * E_;
  int k = threadIdx.x * 4;
  f32x4 v = *(const f32x4*)(src + k);
  dst[k + 0] = __float2bfloat16(v[0]);
  dst[k + 1] = __float2bfloat16(v[1]);
  dst[k + 2] = __float2bfloat16(v[2]);
  dst[k + 3] = __float2bfloat16(v[3]);
}

__global__ void cvt_wihx(const float* __restrict__ Wih, bf16* __restrict__ Wx) {
  int j = blockIdx.x;
  int k = threadIdx.x * 4;
  f32x4 v = *(const f32x4*)(Wih + (size_t)j * 1024 + k);
  bf16* d = Wx + (size_t)j * 512 + k;
  d[0] = __float2bfloat16(v[0]);
  d[1] = __float2bfloat16(v[1]);
  d[2] = __float2bfloat16(v[2]);
  d[3] = __float2bfloat16(v[3]);
}

// h0 = tanh(image @ init_h_W.T + b) -> h32init [b][i], hbf buf0 (swizzled hi/lo)
__global__ void h0_kernel(const float* __restrict__ img, const float* __restrict__ W,
                          const float* __restrict__ bias, float* __restrict__ h32,
                          bf16* __restrict__ hbf0) {
  __shared__ float sim[B_][E_ + 1];
  int tid = threadIdx.x;
  for (int i = tid; i < B_ * E_ / 4; i += 256) {
    f32x4 v = ((const f32x4*)img)[i];
    int r = (i * 4) / E_, c = (i * 4) % E_;
    sim[r][c + 0] = v[0]; sim[r][c + 1] = v[1]; sim[r][c + 2] = v[2]; sim[r][c + 3] = v[3];
  }
  __syncthreads();
  int b = tid & 31, il = tid >> 5;
  int i = blockIdx.x * 8 + il;
  const float* wr = W + (size_t)i * E_;
  float acc = 0.f;
  for (int k = 0; k < E_; k += 4) {
    f32x4 w4 = *(const f32x4*)(wr + k);
    acc += w4[0] * sim[b][k] + w4[1] * sim[b][k + 1] + w4[2] * sim[b][k + 2] + w4[3] * sim[b][k + 3];
  }
  float hv = tanhf(acc + bias[i]);
  h32[b * H_ + i] = hv;
  bf16 h16 = __float2bfloat16(hv);
  int off = hswz(b, i);
  hbf0[off] = h16;
  hbf0[32768 + off] = __float2bfloat16(hv - __bfloat162float(h16));
}

__global__ void uv_kernel(const float* __restrict__ img, const float* __restrict__ retr,
                          const float* __restrict__ Wih, float* __restrict__ u,
                          float* __restrict__ v) {
  int blk = blockIdx.x;
  bool isU = blk < 384;
  const float* src = isU ? img : retr;
  float* dst = isU ? u : v;
  int j0 = (isU ? blk : blk - 384) * 8;
  __shared__ float sim[B_][E_ + 1];
  int tid = threadIdx.x;
  for (int i = tid; i < B_ * E_ / 4; i += 256) {
    f32x4 vv = ((const f32x4*)src)[i];
    int r = (i * 4) / E_, c = (i * 4) % E_;
    sim[r][c + 0] = vv[0]; sim[r][c + 1] = vv[1]; sim[r][c + 2] = vv[2]; sim[r][c + 3] = vv[3];
  }
  __syncthreads();
  int b = tid & 31;
  int j = j0 + (tid >> 5);
  const float* wr = Wih + (size_t)j * 1024 + 512;
  float acc = 0.f;
  for (int k = 0; k < E_; k += 4) {
    f32x4 w4 = *(const f32x4*)(wr + k);
    acc += w4[0] * sim[b][k] + w4[1] * sim[b][k + 1] + w4[2] * sim[b][k + 2] + w4[3] * sim[b][k + 3];
  }
  dst[b * H3_ + j] = acc;
}

__global__ void cgate_kernel(const float* __restrict__ img, const float* __restrict__ retr,
                             const float* __restrict__ gW, const float* __restrict__ gb,
                             float* __restrict__ cg) {
  int b = blockIdx.x, tid = threadIdx.x;
  float acc = 0.f;
  for (int k = tid; k < E_; k += 256)
    acc += img[b * E_ + k] * gW[1024 + k] + retr[b * E_ + k] * gW[1536 + k];
  __shared__ float red[256];
  red[tid] = acc;
  __syncthreads();
  for (int s = 128; s > 0; s >>= 1) {
    if (tid < s) red[tid] += red[tid + s];
    __syncthreads();
  }
  if (tid == 0) cg[b] = red[0] + gb[0];
}

// ---------------- low-contention step sync ----------------
// Monotonic per-block step-stamps in distinct 128B lines. One RELEASE store by
// thread 0 (publishes this block's writes), RELAXED parallel polling by wave 0
// (no buffer_inv per poll), single ACQUIRE fence once all stamps reached val.
__device__ __forceinline__ void step_sync(unsigned* flags, int bi, unsigned val) {
  __syncthreads();  // drains this block's vmem (compiler emits vmcnt(0) before s_barrier)
  if (threadIdx.x == 0)
    __hip_atomic_store(flags + bi * 32, val, __ATOMIC_RELEASE, __HIP_MEMORY_SCOPE_AGENT);
  if (threadIdx.x < NBLK) {
    const unsigned* f = flags + threadIdx.x * 32;
    while (__hip_atomic_load(f, __ATOMIC_RELAXED, __HIP_MEMORY_SCOPE_AGENT) < val)
      __builtin_amdgcn_s_sleep(1);
  }
  __syncthreads();
  __builtin_amdgcn_fence(__ATOMIC_ACQUIRE, "agent");
}

// ---------------- persistent GRU recurrence ----------------
// 64 blocks x 256 threads. Block bi owns i-slice [bi*16, bi*16+16) of all 3 gates.
// Whh hi/lo slice lives in registers as MFMA B-fragments (wave w = K-chunk w*256).
__global__ __launch_bounds__(256, 1) void gru_persist(
    const bf16* __restrict__ WhhHi, const bf16* __restrict__ WhhLo,
    const float* __restrict__ gixAll, const float* __restrict__ u,
    const float* __restrict__ v, const float* __restrict__ cg,
    const float* __restrict__ gW, const float* __restrict__ bih,
    const float* __restrict__ bhh, const float* __restrict__ h32init,
    bf16* __restrict__ hbf, float* __restrict__ pg, unsigned* __restrict__ flags,
    bf16* __restrict__ Hb) {
  int bi = blockIdx.x;
  int tid = threadIdx.x;
  int w = tid >> 6, l = tid & 63;
  int lr = l & 15, lk8 = (l >> 4) * 8;
  int kbase = w * 256;

  __shared__ float red[4][3][2][64][4];  // 24KB: [kchunk][gate][btile][lane][reg]
  __shared__ float als[8][32];
  __shared__ float alpha_sh[32];
  __shared__ float pgt[32][8];

  // ---- preload Whh hi/lo fragments (192 VGPRs) ----
  bf16x8 whi[3][8], wlo[3][8];
#pragma unroll
  for (int g = 0; g < 3; ++g)
#pragma unroll
    for (int ks = 0; ks < 8; ++ks) {
      size_t off = (size_t)(g * H_ + bi * 16 + lr) * H_ + kbase + ks * 32 + lk8;
      whi[g][ks] = *(const bf16x8*)(WhhHi + off);
      wlo[g][ks] = *(const bf16x8*)(WhhLo + off);
    }

  // ---- per-thread step-invariant scalars (outputs o=2*tid, 2*tid+1) ----
  int bq = tid >> 3;
  int il0 = (tid & 7) * 2;
  float uq[2][3], vq[2][3], biq[2][3], bhq[2][3], gwq[2], hold[2];
#pragma unroll
  for (int q = 0; q < 2; ++q) {
    int ig = bi * 16 + il0 + q;
#pragma unroll
    for (int g = 0; g < 3; ++g) {
      uq[q][g] = u[bq * H3_ + g * H_ + ig];
      vq[q][g] = v[bq * H3_ + g * H_ + ig];
      biq[q][g] = bih[g * H_ + ig];
      bhq[q][g] = bhh[g * H_ + ig];
    }
    gwq[q] = gW[ig];
    hold[q] = h32init[bq * H_ + ig];
  }

  // ---- prologue: pg partial for step 0 ----
  {
    float p = hold[0] * gwq[0] + hold[1] * gwq[1];
    pgt[bq][tid & 7] = p;
    __syncthreads();
    if (tid < 32) {
      float s = 0.f;
#pragma unroll
      for (int j = 0; j < 8; ++j) s += pgt[tid][j];
      pg[bi * 32 + tid] = s;
    }
  }
  step_sync(flags, bi, 1);

  for (int t = 0; t < S_; ++t) {
    int cur = t & 1, nxt = cur ^ 1;

    // ---- alpha from pg[cur] ----
    {
      int b = tid & 31, c = tid >> 5;
      const float* p = pg + cur * 2048 + c * 8 * 32 + b;
      float s = 0.f;
#pragma unroll
      for (int j = 0; j < 8; ++j) s += p[j * 32];
      als[c][b] = s;
    }
    __syncthreads();
    if (tid < 32) {
      float s = cg[tid];
#pragma unroll
      for (int c = 0; c < 8; ++c) s += als[c][tid];
      alpha_sh[tid] = 1.f / (1.f + expf(-s));
    }
    __syncthreads();

    // ---- MFMA: gh partials over this wave's K-chunk ----
    const bf16* hb = hbf + (size_t)cur * 65536;
    f32x4 acc[3][2] = {};
#pragma unroll
    for (int ks = 0; ks < 8; ++ks) {
#pragma unroll
      for (int bt = 0; bt < 2; ++bt) {
        size_t hoff = ((size_t)(bt * 32 + w * 8 + ks) * 64 + l) * 8;
        bf16x8 hh = *(const bf16x8*)(hb + hoff);
        bf16x8 hl = *(const bf16x8*)(hb + 32768 + hoff);
#pragma unroll
        for (int g = 0; g < 3; ++g) {
          acc[g][bt] = __builtin_amdgcn_mfma_f32_16x16x32_bf16(hh, whi[g][ks], acc[g][bt], 0, 0, 0);
          acc[g][bt] = __builtin_amdgcn_mfma_f32_16x16x32_bf16(hl, whi[g][ks], acc[g][bt], 0, 0, 0);
          acc[g][bt] = __builtin_amdgcn_mfma_f32_16x16x32_bf16(hh, wlo[g][ks], acc[g][bt], 0, 0, 0);
        }
      }
    }
#pragma unroll
    for (int g = 0; g < 3; ++g)
#pragma unroll
      for (int bt = 0; bt < 2; ++bt)
        *(f32x4*)&red[w][g][bt][l][0] = acc[g][bt];
    __syncthreads();

    // ---- update: 2 outputs per thread ----
    float a = alpha_sh[bq];
    int btq = bq >> 4, breg = bq & 3, lrow = ((bq & 15) >> 2) * 16;
    const float* gx = gixAll + ((size_t)t * B_ + bq) * H3_;
    float pgp = 0.f;
    bf16* hbn = hbf + (size_t)nxt * 65536;
#pragma unroll
    for (int q = 0; q < 2; ++q) {
      int il = il0 + q;
      int ig = bi * 16 + il;
      int lane = lrow + il;
      float sr = red[0][0][btq][lane][breg] + red[1][0][btq][lane][breg] +
                 red[2][0][btq][lane][breg] + red[3][0][btq][lane][breg];
      float sz = red[0][1][btq][lane][breg] + red[1][1][btq][lane][breg] +
                 red[2][1][btq][lane][breg] + red[3][1][btq][lane][breg];
      float sn = red[0][2][btq][lane][breg] + red[1][2][btq][lane][breg] +
                 red[2][2][btq][lane][breg] + red[3][2][btq][lane][breg];
      float ir = gx[ig] + a * uq[q][0] + (1.f - a) * vq[q][0] + biq[q][0];
      float iz = gx[H_ + ig] + a * uq[q][1] + (1.f - a) * vq[q][1] + biq[q][1];
      float in_ = gx[2 * H_ + ig] + a * uq[q][2] + (1.f - a) * vq[q][2] + biq[q][2];
      float r = 1.f / (1.f + expf(-(ir + sr + bhq[q][0])));
      float z = 1.f / (1.f + expf(-(iz + sz + bhq[q][1])));
      float nn = tanhf(in_ + r * (sn + bhq[q][2]));
      float hv = (1.f - z) * nn + z * hold[q];
      hold[q] = hv;
      bf16 h16 = __float2bfloat16(hv);
      int off = hswz(bq, ig);
      hbn[off] = h16;
      hbn[32768 + off] = __float2bfloat16(hv - __bfloat162float(h16));
      Hb[((size_t)bq * S_ + t) * H_ + ig] = h16;
      pgp += hv * gwq[q];
    }
    pgt[bq][tid & 7] = pgp;
    __syncthreads();
    if (tid < 32) {
      float s = 0.f;
#pragma unroll
      for (int j = 0; j < 8; ++j) s += pgt[tid][j];
      pg[nxt * 2048 + bi * 32 + tid] = s;
    }
    if (t < S_ - 1) step_sync(flags, bi, t + 2);
  }
}

// ---------------- bf16 MFMA GEMM:  C[M,N] = A[M,K] . Bt[N,K]^T (+bias) ----------------
__global__ __launch_bounds__(256) void gemm_bt(const bf16* __restrict__ A,
                                               const bf16* __restrict__ Bt,
                                               const float* __restrict__ bias,
                                               float* __restrict__ C, int M, int N, int K) {
  __shared__ bf16 Ald[128 * 32];
  __shared__ bf16 Bld[128 * 32];
  int nb = gridDim.x;
  int bid = blockIdx.x;
  int swz = bid;
  if ((nb & 7) == 0) swz = (bid & 7) * (nb >> 3) + (bid >> 3);  // XCD-chunked
  int mtiles = M >> 7;
  int tm = swz % mtiles, tn = swz / mtiles;  // tm fast => B-tile reuse in L2
  int tid = threadIdx.x;
  int l = tid & 63, w = tid >> 6;

  const bf16* ga = A + (size_t)(tm * 128 + w * 16 + (l >> 2)) * K + (l & 3) * 8;
  const bf16* gb = Bt + (size_t)(tn * 128 + w * 16 + (l >> 2)) * K + (l & 3) * 8;
  char* lA = (char*)Ald + w * 1024;
  char* lB = (char*)Bld + w * 1024;

  f32x4 acc[4][4] = {};
  int wm = (w >> 1) * 64, wn = (w & 1) * 64;
  int lr = l & 15, lk = (l >> 4) * 8;

  for (int kt = 0; kt < K; kt += 32) {
    async16(lA, ga);
    async16(lA + 4096, ga + (size_t)64 * K);
    async16(lB, gb);
    async16(lB + 4096, gb + (size_t)64 * K);
    ga += 32; gb += 32;
    __syncthreads();
    bf16x8 af[4], bfv[4];
#pragma unroll
    for (int mi = 0; mi < 4; ++mi) af[mi] = *(const bf16x8*)&Ald[(wm + mi * 16 + lr) * 32 + lk];
#pragma unroll
    for (int ni = 0; ni < 4; ++ni) bfv[ni] = *(const bf16x8*)&Bld[(wn + ni * 16 + lr) * 32 + lk];
#pragma unroll
    for (int mi = 0; mi < 4; ++mi)
#pragma unroll
      for (int ni = 0; ni < 4; ++ni)
        acc[mi][ni] = __builtin_amdgcn_mfma_f32_16x16x32_bf16(af[mi], bfv[ni], acc[mi][ni], 0, 0, 0);
    __syncthreads();
  }

  int cr = (l >> 4) * 4, cc = l & 15;
#pragma unroll
  for (int mi = 0; mi < 4; ++mi) {
#pragma unroll
    for (int ni = 0; ni < 4; ++ni) {
      int col = tn * 128 + wn + ni * 16 + cc;
      float bv = bias ? bias[col] : 0.f;
#pragma unroll
      for (int rr = 0; rr < 4; ++rr) {
        int row = tm * 128 + wm + mi * 16 + cr + rr;
        C[(size_t)row * N + col] = acc[mi][ni][rr] + bv;
      }
    }
  }
}

// ---------------- launcher ----------------
extern "C" void kernel_launch(void* const* d_in, const int* in_sizes, int n_in, void* d_out,
                              int out_size, void* d_ws, size_t ws_size, hipStream_t stream) {
  const float* img  = (const float*)d_in[0];
  const float* retr = (const float*)d_in[1];
  const int*   toks = (const int*)d_in[2];
  const float* temb = (const float*)d_in[3];
  const float* ihW  = (const float*)d_in[4];
  const float* ihb  = (const float*)d_in[5];
  const float* Wih  = (const float*)d_in[6];
  const float* Whh  = (const float*)d_in[7];
  const float* bih  = (const float*)d_in[8];
  const float* bhh  = (const float*)d_in[9];
  const float* gW   = (const float*)d_in[10];
  const float* gb   = (const float*)d_in[11];
  const float* outW = (const float*)d_in[12];
  const float* outb = (const float*)d_in[13];
  float* out = (float*)d_out;

  char* ws = (char*)d_ws;
  bf16* Wb     = (bf16*)ws;  ws += (size_t)V_ * H_ * 2;
  float* gix   = (float*)ws; ws += (size_t)S_ * B_ * H3_ * 4;
  bf16* WhhHi  = (bf16*)ws;  ws += (size_t)H3_ * H_ * 2;
  bf16* WhhLo  = (bf16*)ws;  ws += (size_t)H3_ * H_ * 2;
  bf16* Wihx   = (bf16*)ws;  ws += (size_t)H3_ * E_ * 2;
  bf16* Abf    = (bf16*)ws;  ws += (size_t)B_ * S_ * E_ * 2;
  bf16* Hb     = (bf16*)ws;  ws += (size_t)B_ * S_ * H_ * 2;
  float* u     = (float*)ws; ws += (size_t)B_ * H3_ * 4;
  float* v     = (float*)ws; ws += (size_t)B_ * H3_ * 4;
  float* h32i  = (float*)ws; ws += (size_t)B_ * H_ * 4;
  bf16* hbf    = (bf16*)ws;  ws += (size_t)2 * 2 * B_ * H_ * 2;  // [buf][hi|lo] swizzled
  float* pg    = (float*)ws; ws += (size_t)2 * NBLK * B_ * 4;
  float* cg    = (float*)ws; ws += 128;
  unsigned* flags = (unsigned*)ws; ws += NBLK * 32 * 4;  // 128B-spaced step stamps

  // precompute
  cvt_wb<<<2048, 256, 0, stream>>>(outW, (ushort*)Wb, (long)V_ * H_ / 4);
  gather_tok<<<B_ * S_, 128, 0, stream>>>(toks, temb, Abf);
  cvt_wihx<<<H3_, 128, 0, stream>>>(Wih, Wihx);
  gemm_bt<<<(B_ * S_ / 128) * (H3_ / 128), 256, 0, stream>>>(Abf, Wihx, nullptr, gix,
                                                             B_ * S_, H3_, E_);
  cvt_whh<<<H3_ * H_ / 1024, 256, 0, stream>>>(Whh, WhhHi, WhhLo);
  h0_kernel<<<H_ / 8, 256, 0, stream>>>(img, ihW, ihb, h32i, hbf);
  uv_kernel<<<768, 256, 0, stream>>>(img, retr, Wih, u, v);
  cgate_kernel<<<B_, 256, 0, stream>>>(img, retr, gW, gb, cg);
  (void)hipMemsetAsync(flags, 0, NBLK * 32 * 4, stream);

  // persistent recurrence (all 64 steps, one launch)
  gru_persist<<<NBLK, 256, 0, stream>>>(WhhHi, WhhLo, gix, u, v, cg, gW, bih, bhh, h32i,
                                        hbf, pg, flags, Hb);

  // big output GEMM: [2048, 32000] = Hb . Wb^T + out_b
  gemm_bt<<<(B_ * S_ / 128) * (V_ / 128), 256, 0, stream>>>(Hb, Wb, outb, out,
                                                            B_ * S_, V_, H_);
}

// Round 5
// 987.154 us; speedup vs baseline: 1.9051x; 1.1906x over previous
//
#include <hip/hip_runtime.h>
#include <hip/hip_bf16.h>
#include <stdint.h>

#define B_ 32
#define S_ 64
#define E_ 512
#define H_ 1024
#define V_ 32000
#define H3_ 3072
#define NBLK 64   // persistent kernel blocks

typedef __bf16 bf16x8 __attribute__((ext_vector_type(8)));
typedef __bf16 bf16x4 __attribute__((ext_vector_type(4)));
typedef float f32x4 __attribute__((ext_vector_type(4)));
typedef unsigned long long u64_t;
using bf16 = __hip_bfloat16;

__device__ __forceinline__ unsigned short f2bf(float f) {
  __hip_bfloat16 h = __float2bfloat16(f);
  return __builtin_bit_cast(unsigned short, h);
}

__device__ __forceinline__ void async16(void* lds, const void* g) {
  __builtin_amdgcn_global_load_lds(
      (const __attribute__((address_space(1))) unsigned int*)g,
      (__attribute__((address_space(3))) unsigned int*)lds, 16, 0, 0);
}

// MALL-coherent (sc0 sc1) relaxed atomics — bypass L1/L2, coherent at L3.
__device__ __forceinline__ void st_u32(unsigned* p, unsigned v) {
  __hip_atomic_store(p, v, __ATOMIC_RELAXED, __HIP_MEMORY_SCOPE_AGENT);
}
__device__ __forceinline__ unsigned ld_u32(const unsigned* p) {
  return __hip_atomic_load(p, __ATOMIC_RELAXED, __HIP_MEMORY_SCOPE_AGENT);
}
__device__ __forceinline__ u64_t ld_u64(const u64_t* p) {
  return __hip_atomic_load(p, __ATOMIC_RELAXED, __HIP_MEMORY_SCOPE_AGENT);
}

struct Q2 { u64_t a, b; };

// fragment-swizzled h layout: element h[b][ig] lives at this bf16 offset
__device__ __forceinline__ int hswz(int b, int ig) {
  return ((((b >> 4) * 32 + (ig >> 5)) * 64) + ((b & 15) + (((ig >> 3) & 3) << 4))) * 8 + (ig & 7);
}

// ---------------- precompute kernels ----------------

__global__ void cvt_wb(const float* __restrict__ W, ushort* __restrict__ Wb, long n4) {
  long stride = (long)gridDim.x * blockDim.x;
  for (long i = (long)blockIdx.x * blockDim.x + threadIdx.x; i < n4; i += stride) {
    f32x4 v = *(const f32x4*)(W + i * 4);
    ushort4 o;
    o.x = f2bf(v[0]); o.y = f2bf(v[1]); o.z = f2bf(v[2]); o.w = f2bf(v[3]);
    ((ushort4*)Wb)[i] = o;
  }
}

// Whh fp32 -> hi/lo bf16 split
__global__ void cvt_whh(const float* __restrict__ W, bf16* __restrict__ hi,
                        bf16* __restrict__ lo) {
  size_t idx = ((size_t)blockIdx.x * 256 + threadIdx.x) * 4;
  f32x4 v = *(const f32x4*)(W + idx);
#pragma unroll
  for (int j = 0; j < 4; ++j) {
    bf16 h = __float2bfloat16(v[j]);
    hi[idx + j] = h;
    lo[idx + j] = __float2bfloat16(v[j] - __bfloat162float(h));
  }
}

__global__ void gather_tok(const int* __restrict__ toks, const float* __restrict__ emb,
                           bf16* __restrict__ Abf) {
  int m = blockIdx.x;
  int b = m & 31, t = m >> 5;
  int token = toks[b * S_ + t];
  const float* src = emb + (size_t)token * E_;
  bf16* dst = Abf + (size_t)m * E_;
  int k = threadIdx.x * 4;
  f32x4 v = *(const f32x4*)(src + k);
  dst[k + 0] = __float2bfloat16(v[0]);
  dst[k + 1] = __float2bfloat16(v[1]);
  dst[k + 2] = __float2bfloat16(v[2]);
  dst[k + 3] = __float2bfloat16(v[3]);
}

__global__ void cvt_wihx(const float* __restrict__ Wih, bf16* __restrict__ Wx) {
  int j = blockIdx.x;
  int k = threadIdx.x * 4;
  f32x4 v = *(const f32x4*)(Wih + (size_t)j * 1024 + k);
  bf16* d = Wx + (size_t)j * 512 + k;
  d[0] = __float2bfloat16(v[0]);
  d[1] = __float2bfloat16(v[1]);
  d[2] = __float2bfloat16(v[2]);
  d[3] = __float2bfloat16(v[3]);
}

// h0 = tanh(image @ init_h_W.T + b) -> h32init [b][i], hbf buf0 (swizzled hi/lo)
__global__ void h0_kernel(const float* __restrict__ img, const float* __restrict__ W,
                          const float* __restrict__ bias, float* __restrict__ h32,
                          bf16* __restrict__ hbf0) {
  __shared__ float sim[B_][E_ + 1];
  int tid = threadIdx.x;
  for (int i = tid; i < B_ * E_ / 4; i += 256) {
    f32x4 v = ((const f32x4*)img)[i];
    int r = (i * 4) / E_, c = (i * 4) % E_;
    sim[r][c + 0] = v[0]; sim[r][c + 1] = v[1]; sim[r][c + 2] = v[2]; sim[r][c + 3] = v[3];
  }
  __syncthreads();
  int b = tid & 31, il = tid >> 5;
  int i = blockIdx.x * 8 + il;
  const float* wr = W + (size_t)i * E_;
  float acc = 0.f;
  for (int k = 0; k < E_; k += 4) {
    f32x4 w4 = *(const f32x4*)(wr + k);
    acc += w4[0] * sim[b][k] + w4[1] * sim[b][k + 1] + w4[2] * sim[b][k + 2] + w4[3] * sim[b][k + 3];
  }
  float hv = tanhf(acc + bias[i]);
  h32[b * H_ + i] = hv;
  bf16 h16 = __float2bfloat16(hv);
  int off = hswz(b, i);
  hbf0[off] = h16;
  hbf0[32768 + off] = __float2bfloat16(hv - __bfloat162float(h16));
}

__global__ void uv_kernel(const float* __restrict__ img, const float* __restrict__ retr,
                          const float* __restrict__ Wih, float* __restrict__ u,
                          float* __restrict__ v) {
  int blk = blockIdx.x;
  bool isU = blk < 384;
  const float* src = isU ? img : retr;
  float* dst = isU ? u : v;
  int j0 = (isU ? blk : blk - 384) * 8;
  __shared__ float sim[B_][E_ + 1];
  int tid = threadIdx.x;
  for (int i = tid; i < B_ * E_ / 4; i += 256) {
    f32x4 vv = ((const f32x4*)src)[i];
    int r = (i * 4) / E_, c = (i * 4) % E_;
    sim[r][c + 0] = vv[0]; sim[r][c + 1] = vv[1]; sim[r][c + 2] = vv[2]; sim[r][c + 3] = vv[3];
  }
  __syncthreads();
  int b = tid & 31;
  int j = j0 + (tid >> 5);
  const float* wr = Wih + (size_t)j * 1024 + 512;
  float acc = 0.f;
  for (int k = 0; k < E_; k += 4) {
    f32x4 w4 = *(const f32x4*)(wr + k);
    acc += w4[0] * sim[b][k] + w4[1] * sim[b][k + 1] + w4[2] * sim[b][k + 2] + w4[3] * sim[b][k + 3];
  }
  dst[b * H3_ + j] = acc;
}

__global__ void cgate_kernel(const float* __restrict__ img, const float* __restrict__ retr,
                             const float* __restrict__ gW, const float* __restrict__ gb,
                             float* __restrict__ cg) {
  int b = blockIdx.x, tid = threadIdx.x;
  float acc = 0.f;
  for (int k = tid; k < E_; k += 256)
    acc += img[b * E_ + k] * gW[1024 + k] + retr[b * E_ + k] * gW[1536 + k];
  __shared__ float red[256];
  red[tid] = acc;
  __syncthreads();
  for (int s = 128; s > 0; s >>= 1) {
    if (tid < s) red[tid] += red[tid + s];
    __syncthreads();
  }
  if (tid == 0) cg[b] = red[0] + gb[0];
}

// ---------------- fence-free step sync ----------------
// All cross-block data moves via sc0sc1 (MALL-coherent) accesses, so no
// buffer_wbl2 / buffer_inv is ever required. __syncthreads() drains each
// wave's vmem (vmcnt(0) before s_barrier) => all h stores are acked at MALL
// before the flag store. Consumers read h via sc0sc1 loads after the poll.
__device__ __forceinline__ void step_sync(unsigned* flags, int bi, unsigned val) {
  __syncthreads();
  if (threadIdx.x == 0) st_u32(flags + bi * 32, val);
  if (threadIdx.x < NBLK) {
    const unsigned* f = flags + threadIdx.x * 32;
    while (ld_u32(f) < val) __builtin_amdgcn_s_sleep(1);
  }
  __syncthreads();
}

// ---------------- persistent GRU recurrence ----------------
// 64 blocks x 256 threads. Block bi owns i-slice [bi*16, bi*16+16) of all 3 gates.
// Whh hi/lo slice lives in registers as MFMA B-fragments (wave w = K-chunk w*256).
__global__ __launch_bounds__(256, 1) void gru_persist(
    const bf16* __restrict__ WhhHi, const bf16* __restrict__ WhhLo,
    const float* __restrict__ gixAll, const float* __restrict__ u,
    const float* __restrict__ v, const float* __restrict__ cg,
    const float* __restrict__ gW, const float* __restrict__ bih,
    const float* __restrict__ bhh, const float* __restrict__ h32init,
    bf16* __restrict__ hbf, float* __restrict__ pg, unsigned* __restrict__ flags,
    bf16* __restrict__ Hb) {
  int bi = blockIdx.x;
  int tid = threadIdx.x;
  int w = tid >> 6, l = tid & 63;
  int lr = l & 15, lk8 = (l >> 4) * 8;
  int kbase = w * 256;

  __shared__ float red[4][3][2][64][4];  // 24KB: [kchunk][gate][btile][lane][reg]
  __shared__ float als[8][32];
  __shared__ float alpha_sh[32];
  __shared__ float pgt[32][8];

  // ---- preload Whh hi/lo fragments ----
  bf16x8 whi[3][8], wlo[3][8];
#pragma unroll
  for (int g = 0; g < 3; ++g)
#pragma unroll
    for (int ks = 0; ks < 8; ++ks) {
      size_t off = (size_t)(g * H_ + bi * 16 + lr) * H_ + kbase + ks * 32 + lk8;
      whi[g][ks] = *(const bf16x8*)(WhhHi + off);
      wlo[g][ks] = *(const bf16x8*)(WhhLo + off);
    }

  // ---- per-thread step-invariant scalars (outputs o=2*tid, 2*tid+1) ----
  int bq = tid >> 3;
  int il0 = (tid & 7) * 2;
  float uq[2][3], vq[2][3], biq[2][3], bhq[2][3], gwq[2], hold[2];
#pragma unroll
  for (int q = 0; q < 2; ++q) {
    int ig = bi * 16 + il0 + q;
#pragma unroll
    for (int g = 0; g < 3; ++g) {
      uq[q][g] = u[bq * H3_ + g * H_ + ig];
      vq[q][g] = v[bq * H3_ + g * H_ + ig];
      biq[q][g] = bih[g * H_ + ig];
      bhq[q][g] = bhh[g * H_ + ig];
    }
    gwq[q] = gW[ig];
    hold[q] = h32init[bq * H_ + ig];
  }

  // ---- prologue: pg partial for step 0 ----
  {
    float p = hold[0] * gwq[0] + hold[1] * gwq[1];
    pgt[bq][tid & 7] = p;
    __syncthreads();
    if (tid < 32) {
      float s = 0.f;
#pragma unroll
      for (int j = 0; j < 8; ++j) s += pgt[tid][j];
      st_u32((unsigned*)(pg + bi * 32 + tid), __builtin_bit_cast(unsigned, s));
    }
  }
  step_sync(flags, bi, 1);

  for (int t = 0; t < S_; ++t) {
    int cur = t & 1, nxt = cur ^ 1;

    // ---- alpha from pg[cur] ----
    {
      int b = tid & 31, c = tid >> 5;
      const unsigned* p = (const unsigned*)(pg + cur * 2048 + c * 8 * 32 + b);
      float s = 0.f;
#pragma unroll
      for (int j = 0; j < 8; ++j) s += __builtin_bit_cast(float, ld_u32(p + j * 32));
      als[c][b] = s;
    }
    __syncthreads();
    if (tid < 32) {
      float s = cg[tid];
#pragma unroll
      for (int c = 0; c < 8; ++c) s += als[c][tid];
      alpha_sh[tid] = 1.f / (1.f + expf(-s));
    }
    __syncthreads();

    // ---- prefetch gix for this step (plain cached loads, off critical path) ----
    float gxv[2][3];
    {
      const float* gx = gixAll + ((size_t)t * B_ + bq) * H3_;
#pragma unroll
      for (int q = 0; q < 2; ++q) {
        int ig = bi * 16 + il0 + q;
        gxv[q][0] = gx[ig];
        gxv[q][1] = gx[H_ + ig];
        gxv[q][2] = gx[2 * H_ + ig];
      }
    }

    // ---- MFMA: gh partials over this wave's K-chunk (h via MALL-coherent loads) ----
    const u64_t* hb64 = (const u64_t*)hbf + (size_t)cur * 16384;
    f32x4 acc[3][2] = {};
#pragma unroll
    for (int ks = 0; ks < 8; ++ks) {
#pragma unroll
      for (int bt = 0; bt < 2; ++bt) {
        size_t bidx = ((size_t)(bt * 32 + w * 8 + ks) * 64 + l) * 2;
        Q2 qh{ld_u64(hb64 + bidx), ld_u64(hb64 + bidx + 1)};
        Q2 ql{ld_u64(hb64 + 8192 + bidx), ld_u64(hb64 + 8192 + bidx + 1)};
        bf16x8 hh = __builtin_bit_cast(bf16x8, qh);
        bf16x8 hl = __builtin_bit_cast(bf16x8, ql);
#pragma unroll
        for (int g = 0; g < 3; ++g) {
          acc[g][bt] = __builtin_amdgcn_mfma_f32_16x16x32_bf16(hh, whi[g][ks], acc[g][bt], 0, 0, 0);
          acc[g][bt] = __builtin_amdgcn_mfma_f32_16x16x32_bf16(hl, whi[g][ks], acc[g][bt], 0, 0, 0);
          acc[g][bt] = __builtin_amdgcn_mfma_f32_16x16x32_bf16(hh, wlo[g][ks], acc[g][bt], 0, 0, 0);
        }
      }
    }
#pragma unroll
    for (int g = 0; g < 3; ++g)
#pragma unroll
      for (int bt = 0; bt < 2; ++bt)
        *(f32x4*)&red[w][g][bt][l][0] = acc[g][bt];
    __syncthreads();

    // ---- update: 2 outputs per thread ----
    float a = alpha_sh[bq];
    int btq = bq >> 4, breg = bq & 3, lrow = ((bq & 15) >> 2) * 16;
    float pgp = 0.f;
    unsigned short h16[2], l16[2];
#pragma unroll
    for (int q = 0; q < 2; ++q) {
      int il = il0 + q;
      int lane = lrow + il;
      float sr = red[0][0][btq][lane][breg] + red[1][0][btq][lane][breg] +
                 red[2][0][btq][lane][breg] + red[3][0][btq][lane][breg];
      float sz = red[0][1][btq][lane][breg] + red[1][1][btq][lane][breg] +
                 red[2][1][btq][lane][breg] + red[3][1][btq][lane][breg];
      float sn = red[0][2][btq][lane][breg] + red[1][2][btq][lane][breg] +
                 red[2][2][btq][lane][breg] + red[3][2][btq][lane][breg];
      float ir = gxv[q][0] + a * uq[q][0] + (1.f - a) * vq[q][0] + biq[q][0];
      float iz = gxv[q][1] + a * uq[q][1] + (1.f - a) * vq[q][1] + biq[q][1];
      float in_ = gxv[q][2] + a * uq[q][2] + (1.f - a) * vq[q][2] + biq[q][2];
      float r = 1.f / (1.f + expf(-(ir + sr + bhq[q][0])));
      float z = 1.f / (1.f + expf(-(iz + sz + bhq[q][1])));
      float nn = tanhf(in_ + r * (sn + bhq[q][2]));
      float hv = (1.f - z) * nn + z * hold[q];
      hold[q] = hv;
      h16[q] = f2bf(hv);
      float hi_f;
      { __hip_bfloat16 hb = __builtin_bit_cast(__hip_bfloat16, h16[q]); hi_f = __bfloat162float(hb); }
      l16[q] = f2bf(hv - hi_f);
      pgp += hv * gwq[q];
    }
    // packed MALL-coherent stores (pair of consecutive ig)
    {
      unsigned hipack = (unsigned)h16[0] | ((unsigned)h16[1] << 16);
      unsigned lopack = (unsigned)l16[0] | ((unsigned)l16[1] << 16);
      int off = hswz(bq, bi * 16 + il0);  // even
      unsigned* hi32 = (unsigned*)hbf + (size_t)nxt * 32768;
      st_u32(hi32 + (off >> 1), hipack);
      st_u32(hi32 + 16384 + (off >> 1), lopack);
      *(unsigned*)(Hb + ((size_t)bq * S_ + t) * H_ + bi * 16 + il0) = hipack;  // plain store
    }
    pgt[bq][tid & 7] = pgp;
    __syncthreads();
    if (tid < 32) {
      float s = 0.f;
#pragma unroll
      for (int j = 0; j < 8; ++j) s += pgt[tid][j];
      st_u32((unsigned*)(pg + nxt * 2048 + bi * 32 + tid), __builtin_bit_cast(unsigned, s));
    }
    if (t < S_ - 1) step_sync(flags, bi, t + 2);
  }
}

// ---------------- bf16 MFMA GEMM:  C[M,N] = A[M,K] . Bt[N,K]^T (+bias) ----------------
__global__ __launch_bounds__(256) void gemm_bt(const bf16* __restrict__ A,
                                               const bf16* __restrict__ Bt,
                                               const float* __restrict__ bias,
                                               float* __restrict__ C, int M, int N, int K) {
  __shared__ bf16 Ald[128 * 32];
  __shared__ bf16 Bld[128 * 32];
  int nb = gridDim.x;
  int bid = blockIdx.x;
  int swz = bid;
  if ((nb & 7) == 0) swz = (bid & 7) * (nb >> 3) + (bid >> 3);  // XCD-chunked
  int mtiles = M >> 7;
  int tm = swz % mtiles, tn = swz / mtiles;  // tm fast => B-tile reuse in L2
  int tid = threadIdx.x;
  int l = tid & 63, w = tid >> 6;

  const bf16* ga = A + (size_t)(tm * 128 + w * 16 + (l >> 2)) * K + (l & 3) * 8;
  const bf16* gb = Bt + (size_t)(tn * 128 + w * 16 + (l >> 2)) * K + (l & 3) * 8;
  char* lA = (char*)Ald + w * 1024;
  char* lB = (char*)Bld + w * 1024;

  f32x4 acc[4][4] = {};
  int wm = (w >> 1) * 64, wn = (w & 1) * 64;
  int lr = l & 15, lk = (l >> 4) * 8;

  for (int kt = 0; kt < K; kt += 32) {
    async16(lA, ga);
    async16(lA + 4096, ga + (size_t)64 * K);
    async16(lB, gb);
    async16(lB + 4096, gb + (size_t)64 * K);
    ga += 32; gb += 32;
    __syncthreads();
    bf16x8 af[4], bfv[4];
#pragma unroll
    for (int mi = 0; mi < 4; ++mi) af[mi] = *(const bf16x8*)&Ald[(wm + mi * 16 + lr) * 32 + lk];
#pragma unroll
    for (int ni = 0; ni < 4; ++ni) bfv[ni] = *(const bf16x8*)&Bld[(wn + ni * 16 + lr) * 32 + lk];
#pragma unroll
    for (int mi = 0; mi < 4; ++mi)
#pragma unroll
      for (int ni = 0; ni < 4; ++ni)
        acc[mi][ni] = __builtin_amdgcn_mfma_f32_16x16x32_bf16(af[mi], bfv[ni], acc[mi][ni], 0, 0, 0);
    __syncthreads();
  }

  int cr = (l >> 4) * 4, cc = l & 15;
#pragma unroll
  for (int mi = 0; mi < 4; ++mi) {
#pragma unroll
    for (int ni = 0; ni < 4; ++ni) {
      int col = tn * 128 + wn + ni * 16 + cc;
      float bv = bias ? bias[col] : 0.f;
#pragma unroll
      for (int rr = 0; rr < 4; ++rr) {
        int row = tm * 128 + wm + mi * 16 + cr + rr;
        C[(size_t)row * N + col] = acc[mi][ni][rr] + bv;
      }
    }
  }
}

// ---------------- launcher ----------------
extern "C" void kernel_launch(void* const* d_in, const int* in_sizes, int n_in, void* d_out,
                              int out_size, void* d_ws, size_t ws_size, hipStream_t stream) {
  const float* img  = (const float*)d_in[0];
  const float* retr = (const float*)d_in[1];
  const int*   toks = (const int*)d_in[2];
  const float* temb = (const float*)d_in[3];
  const float* ihW  = (const float*)d_in[4];
  const float* ihb  = (const float*)d_in[5];
  const float* Wih  = (const float*)d_in[6];
  const float* Whh  = (const float*)d_in[7];
  const float* bih  = (const float*)d_in[8];
  const float* bhh  = (const float*)d_in[9];
  const float* gW   = (const float*)d_in[10];
  const float* gb   = (const float*)d_in[11];
  const float* outW = (const float*)d_in[12];
  const float* outb = (const float*)d_in[13];
  float* out = (float*)d_out;

  char* ws = (char*)d_ws;
  bf16* Wb     = (bf16*)ws;  ws += (size_t)V_ * H_ * 2;
  float* gix   = (float*)ws; ws += (size_t)S_ * B_ * H3_ * 4;
  bf16* WhhHi  = (bf16*)ws;  ws += (size_t)H3_ * H_ * 2;
  bf16* WhhLo  = (bf16*)ws;  ws += (size_t)H3_ * H_ * 2;
  bf16* Wihx   = (bf16*)ws;  ws += (size_t)H3_ * E_ * 2;
  bf16* Abf    = (bf16*)ws;  ws += (size_t)B_ * S_ * E_ * 2;
  bf16* Hb     = (bf16*)ws;  ws += (size_t)B_ * S_ * H_ * 2;
  float* u     = (float*)ws; ws += (size_t)B_ * H3_ * 4;
  float* v     = (float*)ws; ws += (size_t)B_ * H3_ * 4;
  float* h32i  = (float*)ws; ws += (size_t)B_ * H_ * 4;
  bf16* hbf    = (bf16*)ws;  ws += (size_t)2 * 2 * B_ * H_ * 2;  // [buf][hi|lo] swizzled
  float* pg    = (float*)ws; ws += (size_t)2 * NBLK * B_ * 4;
  float* cg    = (float*)ws; ws += 128;
  unsigned* flags = (unsigned*)ws; ws += NBLK * 32 * 4;  // 128B-spaced step stamps

  // precompute
  cvt_wb<<<2048, 256, 0, stream>>>(outW, (ushort*)Wb, (long)V_ * H_ / 4);
  gather_tok<<<B_ * S_, 128, 0, stream>>>(toks, temb, Abf);
  cvt_wihx<<<H3_, 128, 0, stream>>>(Wih, Wihx);
  gemm_bt<<<(B_ * S_ / 128) * (H3_ / 128), 256, 0, stream>>>(Abf, Wihx, nullptr, gix,
                                                             B_ * S_, H3_, E_);
  cvt_whh<<<H3_ * H_ / 1024, 256, 0, stream>>>(Whh, WhhHi, WhhLo);
  h0_kernel<<<H_ / 8, 256, 0, stream>>>(img, ihW, ihb, h32i, hbf);
  uv_kernel<<<768, 256, 0, stream>>>(img, retr, Wih, u, v);
  cgate_kernel<<<B_, 256, 0, stream>>>(img, retr, gW, gb, cg);
  (void)hipMemsetAsync(flags, 0, NBLK * 32 * 4, stream);

  // persistent recurrence (all 64 steps, one launch)
  gru_persist<<<NBLK, 256, 0, stream>>>(WhhHi, WhhLo, gix, u, v, cg, gW, bih, bhh, h32i,
                                        hbf, pg, flags, Hb);

  // big output GEMM: [2048, 32000] = Hb . Wb^T + out_b
  gemm_bt<<<(B_ * S_ / 128) * (V_ / 128), 256, 0, stream>>>(Hb, Wb, outb, out,
                                                            B_ * S_, V_, H_);
}

// Round 6
// 603.217 us; speedup vs baseline: 3.1176x; 1.6365x over previous
//
#include <hip/hip_runtime.h>
#include <hip/hip_bf16.h>
#include <stdint.h>

#define B_ 32
#define S_ 64
#define E_ 512
#define H_ 1024
#define V_ 32000
#define H3_ 3072
#define NBLK 64   // persistent kernel blocks

typedef __bf16 bf16x8 __attribute__((ext_vector_type(8)));
typedef float f32x4 __attribute__((ext_vector_type(4)));
typedef unsigned long long u64_t;
using bf16 = __hip_bfloat16;

__device__ __forceinline__ unsigned short f2bf(float f) {
  __hip_bfloat16 h = __float2bfloat16(f);
  return __builtin_bit_cast(unsigned short, h);
}

__device__ __forceinline__ void async16(void* lds, const void* g) {
  __builtin_amdgcn_global_load_lds(
      (const __attribute__((address_space(1))) unsigned int*)g,
      (__attribute__((address_space(3))) unsigned int*)lds, 16, 0, 0);
}

// MALL-coherent (sc0 sc1) accesses — bypass L1/L2, coherent at Infinity Cache.
__device__ __forceinline__ void st_u32(unsigned* p, unsigned v) {
  __hip_atomic_store(p, v, __ATOMIC_RELAXED, __HIP_MEMORY_SCOPE_AGENT);
}
__device__ __forceinline__ unsigned ld_u32(const unsigned* p) {
  return __hip_atomic_load(p, __ATOMIC_RELAXED, __HIP_MEMORY_SCOPE_AGENT);
}
// 16B MALL-coherent load (no 128b atomics exist; manual vmcnt discipline below).
__device__ __forceinline__ f32x4 ld16_mall(const void* p) {
  f32x4 r;
  asm volatile("global_load_dwordx4 %0, %1, off sc0 sc1" : "=v"(r) : "v"(p));
  return r;
}

// fragment-swizzled h layout: element h[b][ig] lives at this bf16 offset
__device__ __forceinline__ int hswz(int b, int ig) {
  return ((((b >> 4) * 32 + (ig >> 5)) * 64) + ((b & 15) + (((ig >> 3) & 3) << 4))) * 8 + (ig & 7);
}

// ---------------- precompute kernels ----------------

__global__ void cvt_wb(const float* __restrict__ W, ushort* __restrict__ Wb, long n4) {
  long stride = (long)gridDim.x * blockDim.x;
  for (long i = (long)blockIdx.x * blockDim.x + threadIdx.x; i < n4; i += stride) {
    f32x4 v = *(const f32x4*)(W + i * 4);
    ushort4 o;
    o.x = f2bf(v[0]); o.y = f2bf(v[1]); o.z = f2bf(v[2]); o.w = f2bf(v[3]);
    ((ushort4*)Wb)[i] = o;
  }
}

// Whh fp32 -> hi/lo bf16 split
__global__ void cvt_whh(const float* __restrict__ W, bf16* __restrict__ hi,
                        bf16* __restrict__ lo) {
  size_t idx = ((size_t)blockIdx.x * 256 + threadIdx.x) * 4;
  f32x4 v = *(const f32x4*)(W + idx);
#pragma unroll
  for (int j = 0; j < 4; ++j) {
    bf16 h = __float2bfloat16(v[j]);
    hi[idx + j] = h;
    lo[idx + j] = __float2bfloat16(v[j] - __bfloat162float(h));
  }
}

__global__ void gather_tok(const int* __restrict__ toks, const float* __restrict__ emb,
                           bf16* __restrict__ Abf) {
  int m = blockIdx.x;
  int b = m & 31, t = m >> 5;
  int token = toks[b * S_ + t];
  const float* src = emb + (size_t)token * E_;
  bf16* dst = Abf + (size_t)m * E_;
  int k = threadIdx.x * 4;
  f32x4 v = *(const f32x4*)(src + k);
  dst[k + 0] = __float2bfloat16(v[0]);
  dst[k + 1] = __float2bfloat16(v[1]);
  dst[k + 2] = __float2bfloat16(v[2]);
  dst[k + 3] = __float2bfloat16(v[3]);
}

__global__ void cvt_wihx(const float* __restrict__ Wih, bf16* __restrict__ Wx) {
  int j = blockIdx.x;
  int k = threadIdx.x * 4;
  f32x4 v = *(const f32x4*)(Wih + (size_t)j * 1024 + k);
  bf16* d = Wx + (size_t)j * 512 + k;
  d[0] = __float2bfloat16(v[0]);
  d[1] = __float2bfloat16(v[1]);
  d[2] = __float2bfloat16(v[2]);
  d[3] = __float2bfloat16(v[3]);
}

// h0 = tanh(image @ init_h_W.T + b) -> h32init [b][i], hbf buf0 (swizzled hi)
__global__ void h0_kernel(const float* __restrict__ img, const float* __restrict__ W,
                          const float* __restrict__ bias, float* __restrict__ h32,
                          bf16* __restrict__ hbf0) {
  __shared__ float sim[B_][E_ + 1];
  int tid = threadIdx.x;
  for (int i = tid; i < B_ * E_ / 4; i += 256) {
    f32x4 v = ((const f32x4*)img)[i];
    int r = (i * 4) / E_, c = (i * 4) % E_;
    sim[r][c + 0] = v[0]; sim[r][c + 1] = v[1]; sim[r][c + 2] = v[2]; sim[r][c + 3] = v[3];
  }
  __syncthreads();
  int b = tid & 31, il = tid >> 5;
  int i = blockIdx.x * 8 + il;
  const float* wr = W + (size_t)i * E_;
  float acc = 0.f;
  for (int k = 0; k < E_; k += 4) {
    f32x4 w4 = *(const f32x4*)(wr + k);
    acc += w4[0] * sim[b][k] + w4[1] * sim[b][k + 1] + w4[2] * sim[b][k + 2] + w4[3] * sim[b][k + 3];
  }
  float hv = tanhf(acc + bias[i]);
  h32[b * H_ + i] = hv;
  hbf0[hswz(b, i)] = __float2bfloat16(hv);
}

__global__ void uv_kernel(const float* __restrict__ img, const float* __restrict__ retr,
                          const float* __restrict__ Wih, float* __restrict__ u,
                          float* __restrict__ v) {
  int blk = blockIdx.x;
  bool isU = blk < 384;
  const float* src = isU ? img : retr;
  float* dst = isU ? u : v;
  int j0 = (isU ? blk : blk - 384) * 8;
  __shared__ float sim[B_][E_ + 1];
  int tid = threadIdx.x;
  for (int i = tid; i < B_ * E_ / 4; i += 256) {
    f32x4 vv = ((const f32x4*)src)[i];
    int r = (i * 4) / E_, c = (i * 4) % E_;
    sim[r][c + 0] = vv[0]; sim[r][c + 1] = vv[1]; sim[r][c + 2] = vv[2]; sim[r][c + 3] = vv[3];
  }
  __syncthreads();
  int b = tid & 31;
  int j = j0 + (tid >> 5);
  const float* wr = Wih + (size_t)j * 1024 + 512;
  float acc = 0.f;
  for (int k = 0; k < E_; k += 4) {
    f32x4 w4 = *(const f32x4*)(wr + k);
    acc += w4[0] * sim[b][k] + w4[1] * sim[b][k + 1] + w4[2] * sim[b][k + 2] + w4[3] * sim[b][k + 3];
  }
  dst[b * H3_ + j] = acc;
}

__global__ void cgate_kernel(const float* __restrict__ img, const float* __restrict__ retr,
                             const float* __restrict__ gW, const float* __restrict__ gb,
                             float* __restrict__ cg) {
  int b = blockIdx.x, tid = threadIdx.x;
  float acc = 0.f;
  for (int k = tid; k < E_; k += 256)
    acc += img[b * E_ + k] * gW[1024 + k] + retr[b * E_ + k] * gW[1536 + k];
  __shared__ float red[256];
  red[tid] = acc;
  __syncthreads();
  for (int s = 128; s > 0; s >>= 1) {
    if (tid < s) red[tid] += red[tid + s];
    __syncthreads();
  }
  if (tid == 0) cg[b] = red[0] + gb[0];
}

// ---------------- fence-free step sync ----------------
__device__ __forceinline__ void step_sync(unsigned* flags, int bi, unsigned val) {
  __syncthreads();  // per-wave vmcnt(0) before s_barrier drains all stores
  if (threadIdx.x == 0) st_u32(flags + bi * 32, val);
  if (threadIdx.x < NBLK) {
    const unsigned* f = flags + threadIdx.x * 32;
    while (ld_u32(f) < val) __builtin_amdgcn_s_sleep(1);
  }
  __syncthreads();
}

// ---------------- persistent GRU recurrence ----------------
// 64 blocks x 256 threads. Block bi owns i-slice [bi*16, bi*16+16) of all 3 gates.
// Whh hi/lo slice in registers as MFMA B-fragments (wave w = K-chunk w*256).
// alpha's h.gW dot rides the same MFMA pass as a 4th "gate" (gW broadcast frag).
__global__ __launch_bounds__(256, 1) void gru_persist(
    const bf16* __restrict__ WhhHi, const bf16* __restrict__ WhhLo,
    const float* __restrict__ gixAll, const float* __restrict__ u,
    const float* __restrict__ v, const float* __restrict__ cg,
    const float* __restrict__ gW, const float* __restrict__ bih,
    const float* __restrict__ bhh, const float* __restrict__ h32init,
    bf16* __restrict__ hbf, unsigned* __restrict__ flags, bf16* __restrict__ Hb) {
  int bi = blockIdx.x;
  int tid = threadIdx.x;
  int w = tid >> 6, l = tid & 63;
  int lr = l & 15, lk8 = (l >> 4) * 8;
  int kbase = w * 256;

  __shared__ float red[4][4][2][64][4];  // 32KB: [kchunk][gate(3=alpha)][btile][lane][reg]

  // ---- preload Whh hi/lo fragments ----
  bf16x8 whi[3][8], wlo[3][8];
#pragma unroll
  for (int g = 0; g < 3; ++g)
#pragma unroll
    for (int ks = 0; ks < 8; ++ks) {
      size_t off = (size_t)(g * H_ + bi * 16 + lr) * H_ + kbase + ks * 32 + lk8;
      whi[g][ks] = *(const bf16x8*)(WhhHi + off);
      wlo[g][ks] = *(const bf16x8*)(WhhLo + off);
    }
  // ---- gW broadcast B-fragments: lane holds gW[k] for its k-slot (all cols equal) ----
  bf16x8 gwf[8];
#pragma unroll
  for (int ks = 0; ks < 8; ++ks) {
    int kk = (w * 8 + ks) * 32 + (l >> 4) * 8;
    f32x4 g0 = *(const f32x4*)(gW + kk);
    f32x4 g1 = *(const f32x4*)(gW + kk + 4);
    bf16x8 gf;
#pragma unroll
    for (int j = 0; j < 4; ++j) {
      gf[j] = __builtin_bit_cast(__bf16, f2bf(g0[j]));
      gf[j + 4] = __builtin_bit_cast(__bf16, f2bf(g1[j]));
    }
    gwf[ks] = gf;
  }

  // ---- per-thread step-invariant scalars (outputs o=2*tid, 2*tid+1) ----
  int bq = tid >> 3;
  int il0 = (tid & 7) * 2;
  float uq[2][3], vq[2][3], biq[2][3], bhq[2][3], hold[2];
  float cgq = cg[bq];
#pragma unroll
  for (int q = 0; q < 2; ++q) {
    int ig = bi * 16 + il0 + q;
#pragma unroll
    for (int g = 0; g < 3; ++g) {
      uq[q][g] = u[bq * H3_ + g * H_ + ig];
      vq[q][g] = v[bq * H3_ + g * H_ + ig];
      biq[q][g] = bih[g * H_ + ig];
      bhq[q][g] = bhh[g * H_ + ig];
    }
    hold[q] = h32init[bq * H_ + ig];
  }
  int btq = bq >> 4, breg = bq & 3, lrow = ((bq & 15) >> 2) * 16;

  for (int t = 0; t < S_; ++t) {
    int cur = t & 1, nxt = cur ^ 1;

    // ---- phase A: batch-issue all 16 h fragments (16B MALL loads) ----
    const char* hb = (const char*)hbf + (size_t)cur * 65536;
    bf16x8 hh_all[2][8];
#pragma unroll
    for (int bt = 0; bt < 2; ++bt)
#pragma unroll
      for (int ks = 0; ks < 8; ++ks) {
        int off = ((bt * 32 + w * 8 + ks) * 64 + l) * 16;
        hh_all[bt][ks] = __builtin_bit_cast(bf16x8, ld16_mall(hb + off));
      }
    // gix for this step (plain cached loads; covered by the same vmcnt drain)
    float gxv[2][3];
    {
      const float* gx = gixAll + ((size_t)t * B_ + bq) * H3_;
#pragma unroll
      for (int q = 0; q < 2; ++q) {
        int ig = bi * 16 + il0 + q;
        gxv[q][0] = gx[ig];
        gxv[q][1] = gx[H_ + ig];
        gxv[q][2] = gx[2 * H_ + ig];
      }
    }
    asm volatile("s_waitcnt vmcnt(0)" ::: "memory");
    __builtin_amdgcn_sched_barrier(0);

    // ---- MFMA: 3 gates (hi+lo W) + alpha dot, over this wave's K-chunk ----
    f32x4 acc[4][2] = {};
#pragma unroll
    for (int ks = 0; ks < 8; ++ks) {
#pragma unroll
      for (int bt = 0; bt < 2; ++bt) {
        bf16x8 hh = hh_all[bt][ks];
        acc[0][bt] = __builtin_amdgcn_mfma_f32_16x16x32_bf16(hh, whi[0][ks], acc[0][bt], 0, 0, 0);
        acc[0][bt] = __builtin_amdgcn_mfma_f32_16x16x32_bf16(hh, wlo[0][ks], acc[0][bt], 0, 0, 0);
        acc[1][bt] = __builtin_amdgcn_mfma_f32_16x16x32_bf16(hh, whi[1][ks], acc[1][bt], 0, 0, 0);
        acc[1][bt] = __builtin_amdgcn_mfma_f32_16x16x32_bf16(hh, wlo[1][ks], acc[1][bt], 0, 0, 0);
        acc[2][bt] = __builtin_amdgcn_mfma_f32_16x16x32_bf16(hh, whi[2][ks], acc[2][bt], 0, 0, 0);
        acc[2][bt] = __builtin_amdgcn_mfma_f32_16x16x32_bf16(hh, wlo[2][ks], acc[2][bt], 0, 0, 0);
        acc[3][bt] = __builtin_amdgcn_mfma_f32_16x16x32_bf16(hh, gwf[ks], acc[3][bt], 0, 0, 0);
      }
    }
#pragma unroll
    for (int g = 0; g < 4; ++g)
#pragma unroll
      for (int bt = 0; bt < 2; ++bt)
        *(f32x4*)&red[w][g][bt][l][0] = acc[g][bt];
    __syncthreads();

    // ---- phase B: update 2 outputs per thread ----
    int lane0 = lrow + il0;
    float ad = red[0][3][btq][lane0][breg] + red[1][3][btq][lane0][breg] +
               red[2][3][btq][lane0][breg] + red[3][3][btq][lane0][breg];
    float a = 1.f / (1.f + expf(-(ad + cgq)));
    unsigned short h16[2];
#pragma unroll
    for (int q = 0; q < 2; ++q) {
      int lane = lrow + il0 + q;
      float sr = red[0][0][btq][lane][breg] + red[1][0][btq][lane][breg] +
                 red[2][0][btq][lane][breg] + red[3][0][btq][lane][breg];
      float sz = red[0][1][btq][lane][breg] + red[1][1][btq][lane][breg] +
                 red[2][1][btq][lane][breg] + red[3][1][btq][lane][breg];
      float sn = red[0][2][btq][lane][breg] + red[1][2][btq][lane][breg] +
                 red[2][2][btq][lane][breg] + red[3][2][btq][lane][breg];
      float ir = gxv[q][0] + a * uq[q][0] + (1.f - a) * vq[q][0] + biq[q][0];
      float iz = gxv[q][1] + a * uq[q][1] + (1.f - a) * vq[q][1] + biq[q][1];
      float in_ = gxv[q][2] + a * uq[q][2] + (1.f - a) * vq[q][2] + biq[q][2];
      float r = 1.f / (1.f + expf(-(ir + sr + bhq[q][0])));
      float z = 1.f / (1.f + expf(-(iz + sz + bhq[q][1])));
      float nn = tanhf(in_ + r * (sn + bhq[q][2]));
      float hv = (1.f - z) * nn + z * hold[q];
      hold[q] = hv;
      h16[q] = f2bf(hv);
    }
    {
      unsigned hipack = (unsigned)h16[0] | ((unsigned)h16[1] << 16);
      int off = hswz(bq, bi * 16 + il0);  // even
      unsigned* hi32 = (unsigned*)hbf + (size_t)nxt * 16384;
      st_u32(hi32 + (off >> 1), hipack);
      *(unsigned*)(Hb + ((size_t)bq * S_ + t) * H_ + bi * 16 + il0) = hipack;  // plain store
    }
    if (t < S_ - 1) step_sync(flags, bi, t + 1);
  }
}

// ---------------- bf16 MFMA GEMM:  C[M,N] = A[M,K] . Bt[N,K]^T (+bias) ----------------
__global__ __launch_bounds__(256) void gemm_bt(const bf16* __restrict__ A,
                                               const bf16* __restrict__ Bt,
                                               const float* __restrict__ bias,
                                               float* __restrict__ C, int M, int N, int K) {
  __shared__ bf16 Ald[128 * 32];
  __shared__ bf16 Bld[128 * 32];
  int nb = gridDim.x;
  int bid = blockIdx.x;
  int swz = bid;
  if ((nb & 7) == 0) swz = (bid & 7) * (nb >> 3) + (bid >> 3);  // XCD-chunked
  int mtiles = M >> 7;
  int tm = swz % mtiles, tn = swz / mtiles;  // tm fast => B-tile reuse in L2
  int tid = threadIdx.x;
  int l = tid & 63, w = tid >> 6;

  const bf16* ga = A + (size_t)(tm * 128 + w * 16 + (l >> 2)) * K + (l & 3) * 8;
  const bf16* gb = Bt + (size_t)(tn * 128 + w * 16 + (l >> 2)) * K + (l & 3) * 8;
  char* lA = (char*)Ald + w * 1024;
  char* lB = (char*)Bld + w * 1024;

  f32x4 acc[4][4] = {};
  int wm = (w >> 1) * 64, wn = (w & 1) * 64;
  int lr = l & 15, lk = (l >> 4) * 8;

  for (int kt = 0; kt < K; kt += 32) {
    async16(lA, ga);
    async16(lA + 4096, ga + (size_t)64 * K);
    async16(lB, gb);
    async16(lB + 4096, gb + (size_t)64 * K);
    ga += 32; gb += 32;
    __syncthreads();
    bf16x8 af[4], bfv[4];
#pragma unroll
    for (int mi = 0; mi < 4; ++mi) af[mi] = *(const bf16x8*)&Ald[(wm + mi * 16 + lr) * 32 + lk];
#pragma unroll
    for (int ni = 0; ni < 4; ++ni) bfv[ni] = *(const bf16x8*)&Bld[(wn + ni * 16 + lr) * 32 + lk];
#pragma unroll
    for (int mi = 0; mi < 4; ++mi)
#pragma unroll
      for (int ni = 0; ni < 4; ++ni)
        acc[mi][ni] = __builtin_amdgcn_mfma_f32_16x16x32_bf16(af[mi], bfv[ni], acc[mi][ni], 0, 0, 0);
    __syncthreads();
  }

  int cr = (l >> 4) * 4, cc = l & 15;
#pragma unroll
  for (int mi = 0; mi < 4; ++mi) {
#pragma unroll
    for (int ni = 0; ni < 4; ++ni) {
      int col = tn * 128 + wn + ni * 16 + cc;
      float bv = bias ? bias[col] : 0.f;
#pragma unroll
      for (int rr = 0; rr < 4; ++rr) {
        int row = tm * 128 + wm + mi * 16 + cr + rr;
        C[(size_t)row * N + col] = acc[mi][ni][rr] + bv;
      }
    }
  }
}

// ---------------- launcher ----------------
extern "C" void kernel_launch(void* const* d_in, const int* in_sizes, int n_in, void* d_out,
                              int out_size, void* d_ws, size_t ws_size, hipStream_t stream) {
  const float* img  = (const float*)d_in[0];
  const float* retr = (const float*)d_in[1];
  const int*   toks = (const int*)d_in[2];
  const float* temb = (const float*)d_in[3];
  const float* ihW  = (const float*)d_in[4];
  const float* ihb  = (const float*)d_in[5];
  const float* Wih  = (const float*)d_in[6];
  const float* Whh  = (const float*)d_in[7];
  const float* bih  = (const float*)d_in[8];
  const float* bhh  = (const float*)d_in[9];
  const float* gW   = (const float*)d_in[10];
  const float* gb   = (const float*)d_in[11];
  const float* outW = (const float*)d_in[12];
  const float* outb = (const float*)d_in[13];
  float* out = (float*)d_out;

  char* ws = (char*)d_ws;
  bf16* Wb     = (bf16*)ws;  ws += (size_t)V_ * H_ * 2;
  float* gix   = (float*)ws; ws += (size_t)S_ * B_ * H3_ * 4;
  bf16* WhhHi  = (bf16*)ws;  ws += (size_t)H3_ * H_ * 2;
  bf16* WhhLo  = (bf16*)ws;  ws += (size_t)H3_ * H_ * 2;
  bf16* Wihx   = (bf16*)ws;  ws += (size_t)H3_ * E_ * 2;
  bf16* Abf    = (bf16*)ws;  ws += (size_t)B_ * S_ * E_ * 2;
  bf16* Hb     = (bf16*)ws;  ws += (size_t)B_ * S_ * H_ * 2;
  float* u     = (float*)ws; ws += (size_t)B_ * H3_ * 4;
  float* v     = (float*)ws; ws += (size_t)B_ * H3_ * 4;
  float* h32i  = (float*)ws; ws += (size_t)B_ * H_ * 4;
  bf16* hbf    = (bf16*)ws;  ws += (size_t)2 * B_ * H_ * 2;  // [buf][hi] swizzled
  float* cg    = (float*)ws; ws += 128;
  unsigned* flags = (unsigned*)ws; ws += NBLK * 32 * 4;  // 128B-spaced step stamps

  // precompute
  cvt_wb<<<2048, 256, 0, stream>>>(outW, (ushort*)Wb, (long)V_ * H_ / 4);
  gather_tok<<<B_ * S_, 128, 0, stream>>>(toks, temb, Abf);
  cvt_wihx<<<H3_, 128, 0, stream>>>(Wih, Wihx);
  gemm_bt<<<(B_ * S_ / 128) * (H3_ / 128), 256, 0, stream>>>(Abf, Wihx, nullptr, gix,
                                                             B_ * S_, H3_, E_);
  cvt_whh<<<H3_ * H_ / 1024, 256, 0, stream>>>(Whh, WhhHi, WhhLo);
  h0_kernel<<<H_ / 8, 256, 0, stream>>>(img, ihW, ihb, h32i, hbf);
  uv_kernel<<<768, 256, 0, stream>>>(img, retr, Wih, u, v);
  cgate_kernel<<<B_, 256, 0, stream>>>(img, retr, gW, gb, cg);
  (void)hipMemsetAsync(flags, 0, NBLK * 32 * 4, stream);

  // persistent recurrence (all 64 steps, one launch)
  gru_persist<<<NBLK, 256, 0, stream>>>(WhhHi, WhhLo, gix, u, v, cg, gW, bih, bhh, h32i,
                                        hbf, flags, Hb);

  // big output GEMM: [2048, 32000] = Hb . Wb^T + out_b
  gemm_bt<<<(B_ * S_ / 128) * (V_ / 128), 256, 0, stream>>>(Hb, Wb, outb, out,
                                                            B_ * S_, V_, H_);
}

// Round 7
// 465.102 us; speedup vs baseline: 4.0434x; 1.2970x over previous
//
#include <hip/hip_runtime.h>
#include <hip/hip_bf16.h>
#include <stdint.h>

#define B_ 32
#define S_ 64
#define E_ 512
#define H_ 1024
#define V_ 32000
#define H3_ 3072
#define NPROD 64    // producer blocks (recurrence)
#define NCONS 192   // consumer blocks (streamed logit GEMM)
#define NGRID (NPROD + NCONS)
#define NPANEL 250  // V / 128
#define NBATCH 16   // S / 4 steps per job-row-block
#define NJOBS (NPANEL * NBATCH)

typedef __bf16 bf16x8 __attribute__((ext_vector_type(8)));
typedef float f32x4 __attribute__((ext_vector_type(4)));
typedef unsigned long long u64_t;
using bf16 = __hip_bfloat16;

__device__ __forceinline__ unsigned short f2bf(float f) {
  __hip_bfloat16 h = __float2bfloat16(f);
  return __builtin_bit_cast(unsigned short, h);
}

__device__ __forceinline__ void async16(void* lds, const void* g) {
  __builtin_amdgcn_global_load_lds(
      (const __attribute__((address_space(1))) unsigned int*)g,
      (__attribute__((address_space(3))) unsigned int*)lds, 16, 0, 0);
}

// MALL-coherent (sc0 sc1) accesses — bypass L1/L2, coherent at Infinity Cache.
__device__ __forceinline__ void st_u32(unsigned* p, unsigned v) {
  __hip_atomic_store(p, v, __ATOMIC_RELAXED, __HIP_MEMORY_SCOPE_AGENT);
}
__device__ __forceinline__ unsigned ld_u32(const unsigned* p) {
  return __hip_atomic_load(p, __ATOMIC_RELAXED, __HIP_MEMORY_SCOPE_AGENT);
}
__device__ __forceinline__ f32x4 ld16_mall(const void* p) {
  f32x4 r;
  asm volatile("global_load_dwordx4 %0, %1, off sc0 sc1" : "=v"(r) : "v"(p));
  return r;
}

// fragment-swizzled h layout: element h[b][ig] lives at this bf16 offset
__device__ __forceinline__ int hswz(int b, int ig) {
  return ((((b >> 4) * 32 + (ig >> 5)) * 64) + ((b & 15) + (((ig >> 3) & 3) << 4))) * 8 + (ig & 7);
}

// ---------------- precompute kernels ----------------

__global__ void cvt_wb(const float* __restrict__ W, ushort* __restrict__ Wb, long n4) {
  long stride = (long)gridDim.x * blockDim.x;
  for (long i = (long)blockIdx.x * blockDim.x + threadIdx.x; i < n4; i += stride) {
    f32x4 v = *(const f32x4*)(W + i * 4);
    ushort4 o;
    o.x = f2bf(v[0]); o.y = f2bf(v[1]); o.z = f2bf(v[2]); o.w = f2bf(v[3]);
    ((ushort4*)Wb)[i] = o;
  }
}

__global__ void cvt_whh(const float* __restrict__ W, bf16* __restrict__ hi,
                        bf16* __restrict__ lo) {
  size_t idx = ((size_t)blockIdx.x * 256 + threadIdx.x) * 4;
  f32x4 v = *(const f32x4*)(W + idx);
#pragma unroll
  for (int j = 0; j < 4; ++j) {
    bf16 h = __float2bfloat16(v[j]);
    hi[idx + j] = h;
    lo[idx + j] = __float2bfloat16(v[j] - __bfloat162float(h));
  }
}

__global__ void gather_tok(const int* __restrict__ toks, const float* __restrict__ emb,
                           bf16* __restrict__ Abf) {
  int m = blockIdx.x;
  int b = m & 31, t = m >> 5;
  int token = toks[b * S_ + t];
  const float* src = emb + (size_t)token * E_;
  bf16* dst = Abf + (size_t)m * E_;
  int k = threadIdx.x * 4;
  f32x4 v = *(const f32x4*)(src + k);
  dst[k + 0] = __float2bfloat16(v[0]);
  dst[k + 1] = __float2bfloat16(v[1]);
  dst[k + 2] = __float2bfloat16(v[2]);
  dst[k + 3] = __float2bfloat16(v[3]);
}

__global__ void cvt_wihx(const float* __restrict__ Wih, bf16* __restrict__ Wx) {
  int j = blockIdx.x;
  int k = threadIdx.x * 4;
  f32x4 v = *(const f32x4*)(Wih + (size_t)j * 1024 + k);
  bf16* d = Wx + (size_t)j * 512 + k;
  d[0] = __float2bfloat16(v[0]);
  d[1] = __float2bfloat16(v[1]);
  d[2] = __float2bfloat16(v[2]);
  d[3] = __float2bfloat16(v[3]);
}

// h0 = tanh(image @ init_h_W.T + b) -> h32init [b][i], hbf slot 0 (swizzled hi)
__global__ void h0_kernel(const float* __restrict__ img, const float* __restrict__ W,
                          const float* __restrict__ bias, float* __restrict__ h32,
                          bf16* __restrict__ hbf0) {
  __shared__ float sim[B_][E_ + 1];
  int tid = threadIdx.x;
  for (int i = tid; i < B_ * E_ / 4; i += 256) {
    f32x4 v = ((const f32x4*)img)[i];
    int r = (i * 4) / E_, c = (i * 4) % E_;
    sim[r][c + 0] = v[0]; sim[r][c + 1] = v[1]; sim[r][c + 2] = v[2]; sim[r][c + 3] = v[3];
  }
  __syncthreads();
  int b = tid & 31, il = tid >> 5;
  int i = blockIdx.x * 8 + il;
  const float* wr = W + (size_t)i * E_;
  float acc = 0.f;
  for (int k = 0; k < E_; k += 4) {
    f32x4 w4 = *(const f32x4*)(wr + k);
    acc += w4[0] * sim[b][k] + w4[1] * sim[b][k + 1] + w4[2] * sim[b][k + 2] + w4[3] * sim[b][k + 3];
  }
  float hv = tanhf(acc + bias[i]);
  h32[b * H_ + i] = hv;
  hbf0[hswz(b, i)] = __float2bfloat16(hv);
}

__global__ void uv_kernel(const float* __restrict__ img, const float* __restrict__ retr,
                          const float* __restrict__ Wih, float* __restrict__ u,
                          float* __restrict__ v) {
  int blk = blockIdx.x;
  bool isU = blk < 384;
  const float* src = isU ? img : retr;
  float* dst = isU ? u : v;
  int j0 = (isU ? blk : blk - 384) * 8;
  __shared__ float sim[B_][E_ + 1];
  int tid = threadIdx.x;
  for (int i = tid; i < B_ * E_ / 4; i += 256) {
    f32x4 vv = ((const f32x4*)src)[i];
    int r = (i * 4) / E_, c = (i * 4) % E_;
    sim[r][c + 0] = vv[0]; sim[r][c + 1] = vv[1]; sim[r][c + 2] = vv[2]; sim[r][c + 3] = vv[3];
  }
  __syncthreads();
  int b = tid & 31;
  int j = j0 + (tid >> 5);
  const float* wr = Wih + (size_t)j * 1024 + 512;
  float acc = 0.f;
  for (int k = 0; k < E_; k += 4) {
    f32x4 w4 = *(const f32x4*)(wr + k);
    acc += w4[0] * sim[b][k] + w4[1] * sim[b][k + 1] + w4[2] * sim[b][k + 2] + w4[3] * sim[b][k + 3];
  }
  dst[b * H3_ + j] = acc;
}

__global__ void cgate_kernel(const float* __restrict__ img, const float* __restrict__ retr,
                             const float* __restrict__ gW, const float* __restrict__ gb,
                             float* __restrict__ cg) {
  int b = blockIdx.x, tid = threadIdx.x;
  float acc = 0.f;
  for (int k = tid; k < E_; k += 256)
    acc += img[b * E_ + k] * gW[1024 + k] + retr[b * E_ + k] * gW[1536 + k];
  __shared__ float red[256];
  red[tid] = acc;
  __syncthreads();
  for (int s = 128; s > 0; s >>= 1) {
    if (tid < s) red[tid] += red[tid + s];
    __syncthreads();
  }
  if (tid == 0) cg[b] = red[0] + gb[0];
}

// ---------------- fence-free producer step sync ----------------
__device__ __forceinline__ void step_sync(unsigned* flags, int bi, unsigned val) {
  __syncthreads();  // per-wave vmcnt(0) before s_barrier drains all stores
  if (threadIdx.x == 0) st_u32(flags + bi * 32, val);
  if (threadIdx.x < NPROD) {
    const unsigned* f = flags + threadIdx.x * 32;
    while (ld_u32(f) < val) __builtin_amdgcn_s_sleep(1);
  }
  __syncthreads();
}

// ---------------- fused persistent kernel ----------------
// Blocks 0..63: GRU recurrence (h slot t -> slot t+1, flag = t+1 when done).
// Blocks 64..255: streamed logit GEMM consuming h slots as they appear.
__global__ __launch_bounds__(256, 1) void fused_persist(
    const bf16* __restrict__ WhhHi, const bf16* __restrict__ WhhLo,
    const float* __restrict__ gixAll, const float* __restrict__ u,
    const float* __restrict__ v, const float* __restrict__ cg,
    const float* __restrict__ gW, const float* __restrict__ bih,
    const float* __restrict__ bhh, const float* __restrict__ h32init,
    bf16* __restrict__ hbf, unsigned* __restrict__ flags,
    const bf16* __restrict__ Wb, const float* __restrict__ outb,
    float* __restrict__ out) {
  __shared__ __align__(16) char smem[32768];
  int bi = blockIdx.x;
  int tid = threadIdx.x;

  if (bi < NPROD) {
    // ================= PRODUCER =================
    int w = tid >> 6, l = tid & 63;
    int lr = l & 15, lk8 = (l >> 4) * 8;
    int kbase = w * 256;
    float(*red)[4][2][64][4] = (float(*)[4][2][64][4])smem;  // [kchunk][gate][bt][lane][reg]

    bf16x8 whi[3][8], wlo[3][8];
#pragma unroll
    for (int g = 0; g < 3; ++g)
#pragma unroll
      for (int ks = 0; ks < 8; ++ks) {
        size_t off = (size_t)(g * H_ + bi * 16 + lr) * H_ + kbase + ks * 32 + lk8;
        whi[g][ks] = *(const bf16x8*)(WhhHi + off);
        wlo[g][ks] = *(const bf16x8*)(WhhLo + off);
      }
    bf16x8 gwf[8];
#pragma unroll
    for (int ks = 0; ks < 8; ++ks) {
      int kk = (w * 8 + ks) * 32 + (l >> 4) * 8;
      f32x4 g0 = *(const f32x4*)(gW + kk);
      f32x4 g1 = *(const f32x4*)(gW + kk + 4);
      bf16x8 gf;
#pragma unroll
      for (int j = 0; j < 4; ++j) {
        gf[j] = __builtin_bit_cast(__bf16, f2bf(g0[j]));
        gf[j + 4] = __builtin_bit_cast(__bf16, f2bf(g1[j]));
      }
      gwf[ks] = gf;
    }

    int bq = tid >> 3;
    int il0 = (tid & 7) * 2;
    float uq[2][3], vq[2][3], biq[2][3], bhq[2][3], hold[2];
    float cgq = cg[bq];
#pragma unroll
    for (int q = 0; q < 2; ++q) {
      int ig = bi * 16 + il0 + q;
#pragma unroll
      for (int g = 0; g < 3; ++g) {
        uq[q][g] = u[bq * H3_ + g * H_ + ig];
        vq[q][g] = v[bq * H3_ + g * H_ + ig];
        biq[q][g] = bih[g * H_ + ig];
        bhq[q][g] = bhh[g * H_ + ig];
      }
      hold[q] = h32init[bq * H_ + ig];
    }
    int btq = bq >> 4, breg = bq & 3, lrow = ((bq & 15) >> 2) * 16;

    for (int t = 0; t < S_; ++t) {
      // phase A: batch-issue all 16 h fragments from slot t (16B MALL loads)
      const char* hb = (const char*)hbf + (size_t)t * 65536;
      bf16x8 hh_all[2][8];
#pragma unroll
      for (int bt = 0; bt < 2; ++bt)
#pragma unroll
        for (int ks = 0; ks < 8; ++ks) {
          int off = ((bt * 32 + w * 8 + ks) * 64 + l) * 16;
          hh_all[bt][ks] = __builtin_bit_cast(bf16x8, ld16_mall(hb + off));
        }
      float gxv[2][3];
      {
        const float* gx = gixAll + ((size_t)t * B_ + bq) * H3_;
#pragma unroll
        for (int q = 0; q < 2; ++q) {
          int ig = bi * 16 + il0 + q;
          gxv[q][0] = gx[ig];
          gxv[q][1] = gx[H_ + ig];
          gxv[q][2] = gx[2 * H_ + ig];
        }
      }
      asm volatile("s_waitcnt vmcnt(0)" ::: "memory");
      __builtin_amdgcn_sched_barrier(0);

      f32x4 acc[4][2] = {};
#pragma unroll
      for (int ks = 0; ks < 8; ++ks) {
#pragma unroll
        for (int bt = 0; bt < 2; ++bt) {
          bf16x8 hh = hh_all[bt][ks];
          acc[0][bt] = __builtin_amdgcn_mfma_f32_16x16x32_bf16(hh, whi[0][ks], acc[0][bt], 0, 0, 0);
          acc[0][bt] = __builtin_amdgcn_mfma_f32_16x16x32_bf16(hh, wlo[0][ks], acc[0][bt], 0, 0, 0);
          acc[1][bt] = __builtin_amdgcn_mfma_f32_16x16x32_bf16(hh, whi[1][ks], acc[1][bt], 0, 0, 0);
          acc[1][bt] = __builtin_amdgcn_mfma_f32_16x16x32_bf16(hh, wlo[1][ks], acc[1][bt], 0, 0, 0);
          acc[2][bt] = __builtin_amdgcn_mfma_f32_16x16x32_bf16(hh, whi[2][ks], acc[2][bt], 0, 0, 0);
          acc[2][bt] = __builtin_amdgcn_mfma_f32_16x16x32_bf16(hh, wlo[2][ks], acc[2][bt], 0, 0, 0);
          acc[3][bt] = __builtin_amdgcn_mfma_f32_16x16x32_bf16(hh, gwf[ks], acc[3][bt], 0, 0, 0);
        }
      }
#pragma unroll
      for (int g = 0; g < 4; ++g)
#pragma unroll
        for (int bt = 0; bt < 2; ++bt)
          *(f32x4*)&red[w][g][bt][l][0] = acc[g][bt];
      __syncthreads();

      // phase B: update 2 outputs per thread; write slot t+1
      int lane0 = lrow + il0;
      float ad = red[0][3][btq][lane0][breg] + red[1][3][btq][lane0][breg] +
                 red[2][3][btq][lane0][breg] + red[3][3][btq][lane0][breg];
      float a = 1.f / (1.f + expf(-(ad + cgq)));
      unsigned short h16[2];
#pragma unroll
      for (int q = 0; q < 2; ++q) {
        int lane = lrow + il0 + q;
        float sr = red[0][0][btq][lane][breg] + red[1][0][btq][lane][breg] +
                   red[2][0][btq][lane][breg] + red[3][0][btq][lane][breg];
        float sz = red[0][1][btq][lane][breg] + red[1][1][btq][lane][breg] +
                   red[2][1][btq][lane][breg] + red[3][1][btq][lane][breg];
        float sn = red[0][2][btq][lane][breg] + red[1][2][btq][lane][breg] +
                   red[2][2][btq][lane][breg] + red[3][2][btq][lane][breg];
        float ir = gxv[q][0] + a * uq[q][0] + (1.f - a) * vq[q][0] + biq[q][0];
        float iz = gxv[q][1] + a * uq[q][1] + (1.f - a) * vq[q][1] + biq[q][1];
        float in_ = gxv[q][2] + a * uq[q][2] + (1.f - a) * vq[q][2] + biq[q][2];
        float r = 1.f / (1.f + expf(-(ir + sr + bhq[q][0])));
        float z = 1.f / (1.f + expf(-(iz + sz + bhq[q][1])));
        float nn = tanhf(in_ + r * (sn + bhq[q][2]));
        float hv = (1.f - z) * nn + z * hold[q];
        hold[q] = hv;
        h16[q] = f2bf(hv);
      }
      {
        unsigned hipack = (unsigned)h16[0] | ((unsigned)h16[1] << 16);
        int off = hswz(bq, bi * 16 + il0);  // even
        unsigned* hi32 = (unsigned*)hbf + (size_t)(t + 1) * 16384;
        st_u32(hi32 + (off >> 1), hipack);
      }
      if (t < S_ - 1) step_sync(flags, bi, t + 1);
    }
    // publish final slot (t=63 wrote slot 64)
    __syncthreads();
    if (tid == 0) st_u32(flags + bi * 32, S_);

  } else {
    // ================= CONSUMER =================
    int c = bi - NPROD;
    int l = tid & 63, w = tid >> 6;
    int wm = (w >> 1) * 64, wn = (w & 1) * 64;
    int lr = l & 15, lk = (l >> 4) * 8;
    bf16* Bld = (bf16*)smem;               // 2 halves of 4096 bf16 (8 KB each)
    char* lB0 = smem + w * 1024;
    const char* hb_base = (const char*)hbf;

    for (int j = c; j < NJOBS; j += NCONS) {
      int batch = j / NPANEL;
      int panel = j - batch * NPANEL;
      int s0 = batch * 4 + 1;              // h slots s0..s0+3
      unsigned need = (unsigned)(batch * 4 + 4);
      if (w == 0) {                        // wave 0 polls, others wait at barrier
        const unsigned* f = flags + l * 32;
        while (ld_u32(f) < need) __builtin_amdgcn_s_sleep(16);
      }
      __builtin_amdgcn_sched_barrier(0);
      __builtin_amdgcn_s_barrier();
      __builtin_amdgcn_sched_barrier(0);

      const bf16* gb = Wb + (size_t)(panel * 128 + w * 16 + (l >> 2)) * 1024 + (l & 3) * 8;
      f32x4 acc[4][4] = {};
      bf16x8 afr[2][4];
#pragma unroll
      for (int mi = 0; mi < 4; ++mi) {     // pre-issue A for kc=0
        int r16 = (wm >> 4) + mi;
        const char* p = hb_base + (size_t)(s0 + (r16 >> 1)) * 65536 +
                        (((r16 & 1) * 32 + 0) * 64 + l) * 16;
        afr[0][mi] = __builtin_bit_cast(bf16x8, ld16_mall(p));
      }
#pragma unroll
      for (int kt = 0; kt < 32; ++kt) {
        char* lB = lB0 + (kt & 1) * 8192;
        async16(lB, gb);
        async16(lB + 4096, gb + (size_t)64 * 1024);
        gb += 32;
        if (kt < 31) {
#pragma unroll
          for (int mi = 0; mi < 4; ++mi) {
            int r16 = (wm >> 4) + mi;
            const char* p = hb_base + (size_t)(s0 + (r16 >> 1)) * 65536 +
                            (((r16 & 1) * 32 + (kt + 1)) * 64 + l) * 16;
            afr[(kt + 1) & 1][mi] = __builtin_bit_cast(bf16x8, ld16_mall(p));
          }
          asm volatile("s_waitcnt vmcnt(4)" ::: "memory");  // B + A_cur done, A_next in flight
        } else {
          asm volatile("s_waitcnt vmcnt(0)" ::: "memory");
        }
        __builtin_amdgcn_sched_barrier(0);
        __builtin_amdgcn_s_barrier();
        __builtin_amdgcn_sched_barrier(0);
        const bf16* Bh = Bld + (kt & 1) * 4096;
        bf16x8 bfv[4];
#pragma unroll
        for (int ni = 0; ni < 4; ++ni)
          bfv[ni] = *(const bf16x8*)&Bh[(wn + ni * 16 + lr) * 32 + lk];
#pragma unroll
        for (int mi = 0; mi < 4; ++mi)
#pragma unroll
          for (int ni = 0; ni < 4; ++ni)
            acc[mi][ni] = __builtin_amdgcn_mfma_f32_16x16x32_bf16(afr[kt & 1][mi], bfv[ni],
                                                                  acc[mi][ni], 0, 0, 0);
      }
      // C write: row gr -> (t = s0-1 + gr/32, b = gr%32)
      int cr = (l >> 4) * 4, cc = l & 15;
#pragma unroll
      for (int mi = 0; mi < 4; ++mi)
#pragma unroll
        for (int ni = 0; ni < 4; ++ni) {
          int col = panel * 128 + wn + ni * 16 + cc;
          float bv = outb[col];
#pragma unroll
          for (int rr = 0; rr < 4; ++rr) {
            int gr = wm + mi * 16 + cr + rr;
            int t = s0 - 1 + (gr >> 5);
            int b = gr & 31;
            out[(size_t)(b * S_ + t) * V_ + col] = acc[mi][ni][rr] + bv;
          }
        }
    }
  }
}

// ---------------- bf16 MFMA GEMM (prologue gix only) ----------------
__global__ __launch_bounds__(256) void gemm_bt(const bf16* __restrict__ A,
                                               const bf16* __restrict__ Bt,
                                               const float* __restrict__ bias,
                                               float* __restrict__ C, int M, int N, int K) {
  __shared__ bf16 Ald[128 * 32];
  __shared__ bf16 Bld[128 * 32];
  int nb = gridDim.x;
  int bid = blockIdx.x;
  int swz = bid;
  if ((nb & 7) == 0) swz = (bid & 7) * (nb >> 3) + (bid >> 3);
  int mtiles = M >> 7;
  int tm = swz % mtiles, tn = swz / mtiles;
  int tid = threadIdx.x;
  int l = tid & 63, w = tid >> 6;

  const bf16* ga = A + (size_t)(tm * 128 + w * 16 + (l >> 2)) * K + (l & 3) * 8;
  const bf16* gb = Bt + (size_t)(tn * 128 + w * 16 + (l >> 2)) * K + (l & 3) * 8;
  char* lA = (char*)Ald + w * 1024;
  char* lB = (char*)Bld + w * 1024;

  f32x4 acc[4][4] = {};
  int wm = (w >> 1) * 64, wn = (w & 1) * 64;
  int lr = l & 15, lk = (l >> 4) * 8;

  for (int kt = 0; kt < K; kt += 32) {
    async16(lA, ga);
    async16(lA + 4096, ga + (size_t)64 * K);
    async16(lB, gb);
    async16(lB + 4096, gb + (size_t)64 * K);
    ga += 32; gb += 32;
    __syncthreads();
    bf16x8 af[4], bfv[4];
#pragma unroll
    for (int mi = 0; mi < 4; ++mi) af[mi] = *(const bf16x8*)&Ald[(wm + mi * 16 + lr) * 32 + lk];
#pragma unroll
    for (int ni = 0; ni < 4; ++ni) bfv[ni] = *(const bf16x8*)&Bld[(wn + ni * 16 + lr) * 32 + lk];
#pragma unroll
    for (int mi = 0; mi < 4; ++mi)
#pragma unroll
      for (int ni = 0; ni < 4; ++ni)
        acc[mi][ni] = __builtin_amdgcn_mfma_f32_16x16x32_bf16(af[mi], bfv[ni], acc[mi][ni], 0, 0, 0);
    __syncthreads();
  }

  int cr = (l >> 4) * 4, cc = l & 15;
#pragma unroll
  for (int mi = 0; mi < 4; ++mi) {
#pragma unroll
    for (int ni = 0; ni < 4; ++ni) {
      int col = tn * 128 + wn + ni * 16 + cc;
      float bv = bias ? bias[col] : 0.f;
#pragma unroll
      for (int rr = 0; rr < 4; ++rr) {
        int row = tm * 128 + wm + mi * 16 + cr + rr;
        C[(size_t)row * N + col] = acc[mi][ni][rr] + bv;
      }
    }
  }
}

// ---------------- launcher ----------------
extern "C" void kernel_launch(void* const* d_in, const int* in_sizes, int n_in, void* d_out,
                              int out_size, void* d_ws, size_t ws_size, hipStream_t stream) {
  const float* img  = (const float*)d_in[0];
  const float* retr = (const float*)d_in[1];
  const int*   toks = (const int*)d_in[2];
  const float* temb = (const float*)d_in[3];
  const float* ihW  = (const float*)d_in[4];
  const float* ihb  = (const float*)d_in[5];
  const float* Wih  = (const float*)d_in[6];
  const float* Whh  = (const float*)d_in[7];
  const float* bih  = (const float*)d_in[8];
  const float* bhh  = (const float*)d_in[9];
  const float* gW   = (const float*)d_in[10];
  const float* gb   = (const float*)d_in[11];
  const float* outW = (const float*)d_in[12];
  const float* outb = (const float*)d_in[13];
  float* out = (float*)d_out;

  char* ws = (char*)d_ws;
  bf16* Wb     = (bf16*)ws;  ws += (size_t)V_ * H_ * 2;
  float* gix   = (float*)ws; ws += (size_t)S_ * B_ * H3_ * 4;
  bf16* WhhHi  = (bf16*)ws;  ws += (size_t)H3_ * H_ * 2;
  bf16* WhhLo  = (bf16*)ws;  ws += (size_t)H3_ * H_ * 2;
  bf16* Wihx   = (bf16*)ws;  ws += (size_t)H3_ * E_ * 2;
  bf16* Abf    = (bf16*)ws;  ws += (size_t)B_ * S_ * E_ * 2;
  float* u     = (float*)ws; ws += (size_t)B_ * H3_ * 4;
  float* v     = (float*)ws; ws += (size_t)B_ * H3_ * 4;
  float* h32i  = (float*)ws; ws += (size_t)B_ * H_ * 4;
  bf16* hbf    = (bf16*)ws;  ws += (size_t)(S_ + 1) * B_ * H_ * 2;  // 65 h slots, swizzled
  float* cg    = (float*)ws; ws += 128;
  unsigned* flags = (unsigned*)ws; ws += NPROD * 32 * 4;

  // precompute
  cvt_wb<<<2048, 256, 0, stream>>>(outW, (ushort*)Wb, (long)V_ * H_ / 4);
  gather_tok<<<B_ * S_, 128, 0, stream>>>(toks, temb, Abf);
  cvt_wihx<<<H3_, 128, 0, stream>>>(Wih, Wihx);
  gemm_bt<<<(B_ * S_ / 128) * (H3_ / 128), 256, 0, stream>>>(Abf, Wihx, nullptr, gix,
                                                             B_ * S_, H3_, E_);
  cvt_whh<<<H3_ * H_ / 1024, 256, 0, stream>>>(Whh, WhhHi, WhhLo);
  h0_kernel<<<H_ / 8, 256, 0, stream>>>(img, ihW, ihb, h32i, hbf);
  uv_kernel<<<768, 256, 0, stream>>>(img, retr, Wih, u, v);
  cgate_kernel<<<B_, 256, 0, stream>>>(img, retr, gW, gb, cg);
  (void)hipMemsetAsync(flags, 0, NPROD * 32 * 4, stream);

  // fused recurrence + streamed logit GEMM (one launch, 256 blocks)
  fused_persist<<<NGRID, 256, 0, stream>>>(WhhHi, WhhLo, gix, u, v, cg, gW, bih, bhh, h32i,
                                           hbf, flags, Wb, outb, out);
}